// Round 1
// baseline (2467.474 us; speedup 1.0000x reference)
//
#include <hip/hip_runtime.h>
#include <hip/hip_bf16.h>
#include <math.h>

// DecoderCell (LFADS): con GRU -> co linear -> gen GRU -> factor projection.
// All stages are row-parallel over B=16384. f32 register-tiled GEMMs,
// 256 threads/block = 8x32 thread grid, 4x4 micro-tile -> 32x128 block tile.
// GRU n-gate uses (r*h) @ W_hn^T (pre-matmul r), so each block computes its
// rows' full r vector first and stashes r*h (bf16) in LDS.

#define NROW   16384
#define GEND   512
#define COND   256
#define COD    128
#define CID    128
#define HD     1280
#define CLIPV  5.0f

__device__ __forceinline__ float sigm(float v) { return 1.0f / (1.0f + __expf(-v)); }

__device__ __forceinline__ void fma_tile(float acc[4][4],
                                         const float (&Ast)[32][36],
                                         const float (&Bs)[32][132],
                                         int ty, int tx)
{
#pragma unroll
    for (int kk = 0; kk < 32; ++kk) {
        const float4 a4 = *reinterpret_cast<const float4*>(&Ast[kk][ty * 4]);
        const float4 b4 = *reinterpret_cast<const float4*>(&Bs[kk][tx * 4]);
        const float av[4] = {a4.x, a4.y, a4.z, a4.w};
        const float bv[4] = {b4.x, b4.y, b4.z, b4.w};
#pragma unroll
        for (int i = 0; i < 4; ++i)
#pragma unroll
            for (int j = 0; j < 4; ++j) acc[i][j] = fmaf(av[i], bv[j], acc[i][j]);
    }
}

// ---------------------------------------------------------------- con GRU ---
__global__ __launch_bounds__(256) void con_cell_kernel(
    const float* __restrict__ x,  const float* __restrict__ h0,
    const float* __restrict__ wih, const float* __restrict__ bih,
    const float* __restrict__ whh, const float* __restrict__ bhh,
    float* out)
{
    __shared__ alignas(16) float Ast[32][36];    // [k][row]
    __shared__ alignas(16) float Bs [32][132];   // [k][col]
    __shared__ __hip_bfloat16 rht[COND][36];     // [k(=hidden col)][row] of r*h

    const int row0 = blockIdx.x * 32;
    const int tid  = threadIdx.x;
    const int ty   = tid >> 5;   // 0..7  -> rows ty*4..+3
    const int tx   = tid & 31;   // 0..31 -> cols tx*4..+3

    auto stageA = [&](int k0) {  // Acat = [x(128) | factor(128) | con_state(256)]
        const float* A; int ld, c0;
        if (k0 < 128)      { A = x;         ld = CID; c0 = k0;       }
        else if (k0 < 256) { A = h0 + 1152; ld = HD;  c0 = k0 - 128; }
        else               { A = h0 + 512;  ld = HD;  c0 = k0 - 256; }
#pragma unroll
        for (int e = 0; e < 4; ++e) {
            int li = tid + (e << 8);
            int rr = li >> 5, kk = li & 31;
            Ast[kk][rr] = A[(row0 + rr) * ld + c0 + kk];
        }
    };
    auto stageB = [&](const float* W, int ldw, int jbase, int c0) {
#pragma unroll
        for (int e = 0; e < 16; ++e) {
            int li = tid + (e << 8);
            int jj = li >> 5, kk = li & 31;
            Bs[kk][jj] = W[(jbase + jj) * ldw + c0 + kk];
        }
    };

    // ---- phase R: r = sigmoid(pre), stash r*h as bf16
    for (int ct = 0; ct < 2; ++ct) {
        float acc[4][4] = {};
        for (int kt = 0; kt < 16; ++kt) {
            int k0 = kt * 32;
            __syncthreads();
            stageA(k0);
            if (k0 < 256) stageB(wih, COND, COND + ct * 128, k0);
            else          stageB(whh, COND, COND + ct * 128, k0 - 256);
            __syncthreads();
            fma_tile(acc, Ast, Bs, ty, tx);
        }
#pragma unroll
        for (int i = 0; i < 4; ++i) {
            int lr = ty * 4 + i, gr = row0 + lr;
#pragma unroll
            for (int j = 0; j < 4; ++j) {
                int col = ct * 128 + tx * 4 + j;
                float rv = sigm(acc[i][j] + bih[COND + col] + bhh[COND + col]);
                float hv = h0[gr * HD + 512 + col];
                rht[col][lr] = __float2bfloat16(rv * hv);
            }
        }
    }

    // ---- phases Z + N (x_n and (r*h)@Whn accumulate into the same acc)
    for (int ct = 0; ct < 2; ++ct) {
        float accZ[4][4] = {}, accN[4][4] = {};
        for (int kt = 0; kt < 16; ++kt) {           // z: K=512
            int k0 = kt * 32;
            __syncthreads();
            stageA(k0);
            if (k0 < 256) stageB(wih, COND, ct * 128, k0);
            else          stageB(whh, COND, ct * 128, k0 - 256);
            __syncthreads();
            fma_tile(accZ, Ast, Bs, ty, tx);
        }
        for (int kt = 0; kt < 8; ++kt) {            // x_n: K=256 (con_input)
            int k0 = kt * 32;
            __syncthreads();
            stageA(k0);
            stageB(wih, COND, 2 * COND + ct * 128, k0);
            __syncthreads();
            fma_tile(accN, Ast, Bs, ty, tx);
        }
        for (int kt = 0; kt < 8; ++kt) {            // (r*h)@Whn^T: K=256
            int k0 = kt * 32;
            __syncthreads();
            stageB(whh, COND, 2 * COND + ct * 128, k0);
            __syncthreads();
#pragma unroll
            for (int kk = 0; kk < 32; ++kk) {
                const float4 b4 = *reinterpret_cast<const float4*>(&Bs[kk][tx * 4]);
                const float bv[4] = {b4.x, b4.y, b4.z, b4.w};
                float av[4];
#pragma unroll
                for (int i = 0; i < 4; ++i)
                    av[i] = __bfloat162float(rht[k0 + kk][ty * 4 + i]);
#pragma unroll
                for (int i = 0; i < 4; ++i)
#pragma unroll
                    for (int j = 0; j < 4; ++j)
                        accN[i][j] = fmaf(av[i], bv[j], accN[i][j]);
            }
        }
#pragma unroll
        for (int i = 0; i < 4; ++i) {
            int lr = ty * 4 + i, gr = row0 + lr;
#pragma unroll
            for (int j = 0; j < 4; ++j) {
                int col = ct * 128 + tx * 4 + j;
                float zv = sigm(accZ[i][j] + bih[col] + bhh[col]);
                float nv = tanhf(accN[i][j] + bih[2 * COND + col] + bhh[2 * COND + col]);
                float hv = h0[gr * HD + 512 + col];
                float hp = zv * hv + (1.0f - zv) * nv;
                out[gr * HD + 512 + col] = fminf(fmaxf(hp, -CLIPV), CLIPV);
            }
        }
    }
}

// ---------------------------------------------------------------- co linear --
__global__ __launch_bounds__(256) void co_kernel(const float* __restrict__ cw,
                                                 const float* __restrict__ cb,
                                                 float* out)
{
    __shared__ alignas(16) float Ast[32][36];
    __shared__ alignas(16) float Bs [32][132];
    const int row0 = blockIdx.x * 32;
    const int jb   = blockIdx.y * 128;
    const int tid = threadIdx.x, ty = tid >> 5, tx = tid & 31;
    float acc[4][4] = {};
    for (int kt = 0; kt < 8; ++kt) {
        int k0 = kt * 32;
        __syncthreads();
#pragma unroll
        for (int e = 0; e < 4; ++e) {
            int li = tid + (e << 8); int rr = li >> 5, kk = li & 31;
            Ast[kk][rr] = out[(row0 + rr) * HD + 512 + k0 + kk];   // con_state_new
        }
#pragma unroll
        for (int e = 0; e < 16; ++e) {
            int li = tid + (e << 8); int jj = li >> 5, kk = li & 31;
            Bs[kk][jj] = cw[(jb + jj) * COND + k0 + kk];
        }
        __syncthreads();
        fma_tile(acc, Ast, Bs, ty, tx);
    }
#pragma unroll
    for (int i = 0; i < 4; ++i) {
        int gr = row0 + ty * 4 + i;
#pragma unroll
        for (int j = 0; j < 4; ++j) {
            int col = jb + tx * 4 + j;
            float v = acc[i][j] + cb[col];
            if (col < COD) {                       // co_mean + gen_input copy
                out[gr * HD +  768 + col] = v;
                out[gr * HD + 1024 + col] = v;
            } else {                               // co_logstd
                out[gr * HD +  896 + (col - COD)] = v;
            }
        }
    }
}

// ---------------------------------------------------------------- gen GRU ---
__global__ __launch_bounds__(256) void gen_cell_kernel(
    const float* __restrict__ h0,
    const float* __restrict__ wih, const float* __restrict__ bih,
    const float* __restrict__ whh, const float* __restrict__ bhh,
    float* out)
{
    __shared__ alignas(16) float Ast[32][36];
    __shared__ alignas(16) float Bs [32][132];
    __shared__ __hip_bfloat16 rht[GEND][36];

    const int row0 = blockIdx.x * 32;
    const int tid  = threadIdx.x;
    const int ty   = tid >> 5;
    const int tx   = tid & 31;

    auto stageA = [&](int k0) {  // Acat = [gen_input(128) | gen_state(512)]
        const float* A; int ld, c0;
        if (k0 < 128) { A = out + 768; ld = HD; c0 = k0;       }
        else          { A = h0;        ld = HD; c0 = k0 - 128; }
#pragma unroll
        for (int e = 0; e < 4; ++e) {
            int li = tid + (e << 8);
            int rr = li >> 5, kk = li & 31;
            Ast[kk][rr] = A[(row0 + rr) * ld + c0 + kk];
        }
    };
    auto stageB = [&](const float* W, int ldw, int jbase, int c0) {
#pragma unroll
        for (int e = 0; e < 16; ++e) {
            int li = tid + (e << 8);
            int jj = li >> 5, kk = li & 31;
            Bs[kk][jj] = W[(jbase + jj) * ldw + c0 + kk];
        }
    };

    // ---- phase R
    for (int ct = 0; ct < 4; ++ct) {
        float acc[4][4] = {};
        for (int kt = 0; kt < 20; ++kt) {           // K = 640
            int k0 = kt * 32;
            __syncthreads();
            stageA(k0);
            if (k0 < 128) stageB(wih, CID,  GEND + ct * 128, k0);
            else          stageB(whh, GEND, GEND + ct * 128, k0 - 128);
            __syncthreads();
            fma_tile(acc, Ast, Bs, ty, tx);
        }
#pragma unroll
        for (int i = 0; i < 4; ++i) {
            int lr = ty * 4 + i, gr = row0 + lr;
#pragma unroll
            for (int j = 0; j < 4; ++j) {
                int col = ct * 128 + tx * 4 + j;
                float rv = sigm(acc[i][j] + bih[GEND + col] + bhh[GEND + col]);
                float hv = h0[gr * HD + col];
                rht[col][lr] = __float2bfloat16(rv * hv);
            }
        }
    }

    // ---- phases Z + N
    for (int ct = 0; ct < 4; ++ct) {
        float accZ[4][4] = {}, accN[4][4] = {};
        for (int kt = 0; kt < 20; ++kt) {           // z: K=640
            int k0 = kt * 32;
            __syncthreads();
            stageA(k0);
            if (k0 < 128) stageB(wih, CID,  ct * 128, k0);
            else          stageB(whh, GEND, ct * 128, k0 - 128);
            __syncthreads();
            fma_tile(accZ, Ast, Bs, ty, tx);
        }
        for (int kt = 0; kt < 4; ++kt) {            // x_n: K=128 (gen_input)
            int k0 = kt * 32;
            __syncthreads();
            stageA(k0);
            stageB(wih, CID, 2 * GEND + ct * 128, k0);
            __syncthreads();
            fma_tile(accN, Ast, Bs, ty, tx);
        }
        for (int kt = 0; kt < 16; ++kt) {           // (r*h)@Whn^T: K=512
            int k0 = kt * 32;
            __syncthreads();
            stageB(whh, GEND, 2 * GEND + ct * 128, k0);
            __syncthreads();
#pragma unroll
            for (int kk = 0; kk < 32; ++kk) {
                const float4 b4 = *reinterpret_cast<const float4*>(&Bs[kk][tx * 4]);
                const float bv[4] = {b4.x, b4.y, b4.z, b4.w};
                float av[4];
#pragma unroll
                for (int i = 0; i < 4; ++i)
                    av[i] = __bfloat162float(rht[k0 + kk][ty * 4 + i]);
#pragma unroll
                for (int i = 0; i < 4; ++i)
#pragma unroll
                    for (int j = 0; j < 4; ++j)
                        accN[i][j] = fmaf(av[i], bv[j], accN[i][j]);
            }
        }
#pragma unroll
        for (int i = 0; i < 4; ++i) {
            int lr = ty * 4 + i, gr = row0 + lr;
#pragma unroll
            for (int j = 0; j < 4; ++j) {
                int col = ct * 128 + tx * 4 + j;
                float zv = sigm(accZ[i][j] + bih[col] + bhh[col]);
                float nv = tanhf(accN[i][j] + bih[2 * GEND + col] + bhh[2 * GEND + col]);
                float hv = h0[gr * HD + col];
                float hp = zv * hv + (1.0f - zv) * nv;
                out[gr * HD + col] = fminf(fmaxf(hp, -CLIPV), CLIPV);
            }
        }
    }
}

// ------------------------------------------------------------ factor proj ---
__global__ __launch_bounds__(256) void fac_kernel(const float* __restrict__ fw,
                                                  float* out)
{
    __shared__ alignas(16) float Ast[32][36];
    __shared__ alignas(16) float Bs [32][132];
    __shared__ float invn[GEND];

    const int row0 = blockIdx.x * 32;
    const int tid = threadIdx.x, ty = tid >> 5, tx = tid & 31;

    // per-block recompute of column-norm reciprocals (fac_w is L2-resident)
    {
        float s0 = 0.f, s1 = 0.f;
        for (int r = 0; r < 128; ++r) {
            float a0 = fw[r * GEND + tid];
            float a1 = fw[r * GEND + tid + 256];
            s0 = fmaf(a0, a0, s0);
            s1 = fmaf(a1, a1, s1);
        }
        invn[tid]       = 1.0f / fmaxf(sqrtf(s0), 1e-12f);
        invn[tid + 256] = 1.0f / fmaxf(sqrtf(s1), 1e-12f);
    }

    float acc[4][4] = {};
    for (int kt = 0; kt < 16; ++kt) {               // K = 512 (gen_state_new)
        int k0 = kt * 32;
        __syncthreads();
#pragma unroll
        for (int e = 0; e < 4; ++e) {
            int li = tid + (e << 8); int rr = li >> 5, kk = li & 31;
            Ast[kk][rr] = out[(row0 + rr) * HD + k0 + kk];
        }
#pragma unroll
        for (int e = 0; e < 16; ++e) {
            int li = tid + (e << 8); int jj = li >> 5, kk = li & 31;
            Bs[kk][jj] = fw[jj * GEND + k0 + kk] * invn[k0 + kk];
        }
        __syncthreads();
        fma_tile(acc, Ast, Bs, ty, tx);
    }
#pragma unroll
    for (int i = 0; i < 4; ++i) {
        int gr = row0 + ty * 4 + i;
#pragma unroll
        for (int j = 0; j < 4; ++j) {
            int col = tx * 4 + j;                   // 0..127
            out[gr * HD + 1152 + col] = acc[i][j];
        }
    }
}

// ----------------------------------------------------------------- launch ---
extern "C" void kernel_launch(void* const* d_in, const int* in_sizes, int n_in,
                              void* d_out, int out_size, void* d_ws, size_t ws_size,
                              hipStream_t stream) {
    const float* x        = (const float*)d_in[0];
    const float* h0       = (const float*)d_in[1];
    const float* con_w_ih = (const float*)d_in[2];
    const float* con_b_ih = (const float*)d_in[3];
    const float* con_w_hh = (const float*)d_in[4];
    const float* con_b_hh = (const float*)d_in[5];
    const float* co_w     = (const float*)d_in[6];
    const float* co_b     = (const float*)d_in[7];
    const float* gen_w_ih = (const float*)d_in[8];
    const float* gen_b_ih = (const float*)d_in[9];
    const float* gen_w_hh = (const float*)d_in[10];
    const float* gen_b_hh = (const float*)d_in[11];
    const float* fac_w    = (const float*)d_in[12];
    float* out = (float*)d_out;

    con_cell_kernel<<<NROW / 32, 256, 0, stream>>>(x, h0, con_w_ih, con_b_ih,
                                                   con_w_hh, con_b_hh, out);
    co_kernel<<<dim3(NROW / 32, 2), 256, 0, stream>>>(co_w, co_b, out);
    gen_cell_kernel<<<NROW / 32, 256, 0, stream>>>(h0, gen_w_ih, gen_b_ih,
                                                   gen_w_hh, gen_b_hh, out);
    fac_kernel<<<NROW / 32, 256, 0, stream>>>(fac_w, out);
}

// Round 2
// 449.919 us; speedup vs baseline: 5.4843x; 5.4843x over previous
//
#include <hip/hip_runtime.h>
#include <math.h>

// DecoderCell (LFADS) on MI355X — bf16 MFMA rewrite.
// Pipeline (all GEMMs, B=16384 rows):
//   1 con_r   : r-gate (256c, K=512)          -> rh bf16 packed at out[0..128)f32
//   2 con_zn  : z (K=512) + n (K=512: x|f|rh) -> con_state out[512..768)
//   3 co_gi   : co_mean (128c, K=256)         -> gen_input out[1024..1152)
//   4 gen_r   : r-gate (512c, K=640)          -> rh bf16 packed at out[768..1024)f32
//   5 gen_zn  : z + n (K=640)                 -> gen_state out[0..512)
//   6 fac     : factors (128c, K=512, norm W) -> out[1152..1280)
//   7 co_final: mean+logstd (256c, K=256)     -> out[768..1024) (rewrites rh region)
// Block tile 128x128, 4 waves (64x64/wave), mfma_f32_16x16x32_bf16,
// K-tile 64 staged f32->bf16 into XOR-swizzled LDS (byte ^= (r&7)<<4).

#define HD    1280
#define NROW  16384
#define CLIPV 5.0f

typedef float  f32x4  __attribute__((ext_vector_type(4)));
typedef __bf16 bf16x8 __attribute__((ext_vector_type(8)));
typedef short  s16x8  __attribute__((ext_vector_type(8)));

struct KSrc {                 // element(row,k), chunk s = k>>7 (static index)
    const void* p[5];
    int         ld[5];
    int         b16[5];
    const float* scale;       // optional per-k scale (fac W only)
};

__device__ __forceinline__ unsigned short f2bf(float f) {
    unsigned u = __float_as_uint(f);
    u = u + 0x7fffu + ((u >> 16) & 1u);
    return (unsigned short)(u >> 16);
}
__device__ __forceinline__ float sigm(float v) { return 1.0f / (1.0f + __expf(-v)); }

// stage 128 rows x 64 k of bf16 into 16 KB LDS tile, swizzled.
__device__ __forceinline__ void stage_tile(char* lds, const void* p_, int ld, int isb16,
                                           const float* scale, int rbase, int k0) {
    const int t = threadIdx.x;
#pragma unroll
    for (int e = 0; e < 2; ++e) {
        const int q    = t + (e << 8);       // 0..511
        const int r    = q >> 2;             // 0..127
        const int kloc = (q & 3) << 4;       // 0,16,32,48
        const int kabs = k0 + kloc;
        unsigned short us[16];
        if (!isb16) {
            const float* p = (const float*)p_ + (size_t)(rbase + r) * ld + kabs;
            float ff[16];
            *(float4*)(ff + 0)  = *(const float4*)(p + 0);
            *(float4*)(ff + 4)  = *(const float4*)(p + 4);
            *(float4*)(ff + 8)  = *(const float4*)(p + 8);
            *(float4*)(ff + 12) = *(const float4*)(p + 12);
            if (scale) {
#pragma unroll
                for (int j = 0; j < 16; ++j) ff[j] *= scale[kabs + j];
            }
#pragma unroll
            for (int j = 0; j < 16; ++j) us[j] = f2bf(ff[j]);
        } else {
            const unsigned* p = (const unsigned*)p_ + (size_t)(rbase + r) * ld + (kabs >> 1);
            uint4 u0 = *(const uint4*)(p + 0);
            uint4 u1 = *(const uint4*)(p + 4);
            const unsigned uu[8] = {u0.x, u0.y, u0.z, u0.w, u1.x, u1.y, u1.z, u1.w};
#pragma unroll
            for (int j = 0; j < 8; ++j) {
                us[2 * j]     = (unsigned short)(uu[j] & 0xffffu);
                us[2 * j + 1] = (unsigned short)(uu[j] >> 16);
            }
        }
        const int swz = (r & 7) << 4;
        s16x8 v0, v1;
#pragma unroll
        for (int j = 0; j < 8; ++j) { v0[j] = (short)us[j]; v1[j] = (short)us[j + 8]; }
        *(s16x8*)(lds + r * 128 + ((((q & 3) << 5) + 0) ^ swz))  = v0;
        *(s16x8*)(lds + r * 128 + ((((q & 3) << 5) + 16) ^ swz)) = v1;
    }
}

__device__ __forceinline__ bf16x8 ldfrag(const char* lds, int r, int ks, int g) {
    const char* p = lds + r * 128 + ((((ks << 2) + g) << 4) ^ ((r & 7) << 4));
    return __builtin_bit_cast(bf16x8, *(const s16x8*)p);
}

template <int K>
__device__ __forceinline__ void gemm_core(f32x4 (&acc)[4][4], char* At, char* Wt,
                                          const KSrc& A, const KSrc& W,
                                          int row0, int wcb) {
    const int l   = threadIdx.x & 63;
    const int w   = threadIdx.x >> 6;
    const int wr  = (w >> 1) << 6;
    const int wc  = (w & 1) << 6;
    const int g   = l >> 4;
    const int r15 = l & 15;
#pragma unroll
    for (int kt = 0; kt < K / 64; ++kt) {
        const int k0 = kt * 64;
        const int s  = k0 >> 7;                    // static (loop unrolled)
        __syncthreads();
        stage_tile(At, A.p[s], A.ld[s], A.b16[s], A.scale, row0, k0);
        stage_tile(Wt, W.p[s], W.ld[s], W.b16[s], W.scale, wcb, k0);
        __syncthreads();
#pragma unroll
        for (int ks = 0; ks < 2; ++ks) {
            bf16x8 a[4], b[4];
#pragma unroll
            for (int f = 0; f < 4; ++f) a[f] = ldfrag(At, wr + f * 16 + r15, ks, g);
#pragma unroll
            for (int f = 0; f < 4; ++f) b[f] = ldfrag(Wt, wc + f * 16 + r15, ks, g);
#pragma unroll
            for (int i = 0; i < 4; ++i)
#pragma unroll
                for (int j = 0; j < 4; ++j)
                    acc[i][j] = __builtin_amdgcn_mfma_f32_16x16x32_bf16(a[i], b[j], acc[i][j], 0, 0, 0);
        }
    }
}

#define EPILOGUE_IDX                                    \
    const int l  = threadIdx.x & 63;                    \
    const int w  = threadIdx.x >> 6;                    \
    const int wr = (w >> 1) << 6;                       \
    const int wc = (w & 1) << 6;

// ------------------------------------------------------------------ con_r ---
__global__ __launch_bounds__(256, 2) void k_con_r(
    const float* __restrict__ x, const float* __restrict__ h0,
    const float* __restrict__ wih, const float* __restrict__ bih,
    const float* __restrict__ whh, const float* __restrict__ bhh, float* out) {
    __shared__ alignas(16) char At[16384], Wt[16384];
    const int col0 = (blockIdx.x & 1) * 128;
    const int row0 = (blockIdx.x >> 1) * 128;
    KSrc A = {{x, h0 + 1152 - 128, h0 + 256, h0 + 256, nullptr},
              {128, HD, HD, HD, 0}, {0, 0, 0, 0, 0}, nullptr};
    KSrc W = {{wih + 256 * 256, wih + 256 * 256, whh + 256 * 256 - 256, whh + 256 * 256 - 256, nullptr},
              {256, 256, 256, 256, 0}, {0, 0, 0, 0, 0}, nullptr};
    f32x4 acc[4][4] = {};
    gemm_core<512>(acc, At, Wt, A, W, row0, col0);
    EPILOGUE_IDX
    unsigned short* outs = (unsigned short*)out;
#pragma unroll
    for (int i = 0; i < 4; ++i)
#pragma unroll
        for (int j = 0; j < 4; ++j)
#pragma unroll
            for (int t = 0; t < 4; ++t) {
                int row = row0 + wr + i * 16 + (l >> 4) * 4 + t;
                int c   = col0 + wc + j * 16 + (l & 15);
                float rv = sigm(acc[i][j][t] + bih[256 + c] + bhh[256 + c]);
                float hv = h0[(size_t)row * HD + 512 + c];
                outs[(size_t)row * 2560 + c] = f2bf(rv * hv);
            }
}

// ----------------------------------------------------------------- con_zn ---
__global__ __launch_bounds__(256, 2) void k_con_zn(
    const float* __restrict__ x, const float* __restrict__ h0,
    const float* __restrict__ wih, const float* __restrict__ bih,
    const float* __restrict__ whh, const float* __restrict__ bhh, float* out) {
    __shared__ alignas(16) char At[16384], Wt[16384];
    const int col0 = (blockIdx.x & 1) * 128;
    const int row0 = (blockIdx.x >> 1) * 128;
    KSrc Az = {{x, h0 + 1152 - 128, h0 + 256, h0 + 256, nullptr},
               {128, HD, HD, HD, 0}, {0, 0, 0, 0, 0}, nullptr};
    KSrc Wz = {{wih, wih, whh - 256, whh - 256, nullptr},
               {256, 256, 256, 256, 0}, {0, 0, 0, 0, 0}, nullptr};
    KSrc An = {{x, h0 + 1152 - 128, (const unsigned*)out - 128, (const unsigned*)out - 128, nullptr},
               {128, HD, HD, HD, 0}, {0, 0, 1, 1, 0}, nullptr};
    KSrc Wn = {{wih + 512 * 256, wih + 512 * 256, whh + 512 * 256 - 256, whh + 512 * 256 - 256, nullptr},
               {256, 256, 256, 256, 0}, {0, 0, 0, 0, 0}, nullptr};
    f32x4 aZ[4][4] = {}, aN[4][4] = {};
    gemm_core<512>(aZ, At, Wt, Az, Wz, row0, col0);
    gemm_core<512>(aN, At, Wt, An, Wn, row0, col0);
    EPILOGUE_IDX
#pragma unroll
    for (int i = 0; i < 4; ++i)
#pragma unroll
        for (int j = 0; j < 4; ++j)
#pragma unroll
            for (int t = 0; t < 4; ++t) {
                int row = row0 + wr + i * 16 + (l >> 4) * 4 + t;
                int c   = col0 + wc + j * 16 + (l & 15);
                float zv = sigm(aZ[i][j][t] + bih[c] + bhh[c]);
                float nv = tanhf(aN[i][j][t] + bih[512 + c] + bhh[512 + c]);
                float hv = h0[(size_t)row * HD + 512 + c];
                float hp = zv * hv + (1.0f - zv) * nv;
                out[(size_t)row * HD + 512 + c] = fminf(fmaxf(hp, -CLIPV), CLIPV);
            }
}

// ------------------------------------------------------------------ co_gi ---
__global__ __launch_bounds__(256, 2) void k_co_gi(
    const float* __restrict__ cw, const float* __restrict__ cb, float* out) {
    __shared__ alignas(16) char At[16384], Wt[16384];
    const int row0 = blockIdx.x * 128;
    KSrc A = {{out + 512, out + 512, nullptr, nullptr, nullptr},
              {HD, HD, 0, 0, 0}, {0, 0, 0, 0, 0}, nullptr};
    KSrc W = {{cw, cw, nullptr, nullptr, nullptr},
              {256, 256, 0, 0, 0}, {0, 0, 0, 0, 0}, nullptr};
    f32x4 acc[4][4] = {};
    gemm_core<256>(acc, At, Wt, A, W, row0, 0);
    EPILOGUE_IDX
#pragma unroll
    for (int i = 0; i < 4; ++i)
#pragma unroll
        for (int j = 0; j < 4; ++j)
#pragma unroll
            for (int t = 0; t < 4; ++t) {
                int row = row0 + wr + i * 16 + (l >> 4) * 4 + t;
                int c   = wc + j * 16 + (l & 15);      // 0..127
                out[(size_t)row * HD + 1024 + c] = acc[i][j][t] + cb[c];
            }
}

// ------------------------------------------------------------------ gen_r ---
__global__ __launch_bounds__(256, 2) void k_gen_r(
    const float* __restrict__ h0,
    const float* __restrict__ wih, const float* __restrict__ bih,
    const float* __restrict__ whh, const float* __restrict__ bhh, float* out) {
    __shared__ alignas(16) char At[16384], Wt[16384];
    const int col0 = (blockIdx.x & 3) * 128;
    const int row0 = (blockIdx.x >> 2) * 128;
    KSrc A = {{out + 1024, h0 - 128, h0 - 128, h0 - 128, h0 - 128},
              {HD, HD, HD, HD, HD}, {0, 0, 0, 0, 0}, nullptr};
    KSrc W = {{wih + 512 * 128, whh + 512 * 512 - 128, whh + 512 * 512 - 128,
               whh + 512 * 512 - 128, whh + 512 * 512 - 128},
              {128, 512, 512, 512, 512}, {0, 0, 0, 0, 0}, nullptr};
    f32x4 acc[4][4] = {};
    gemm_core<640>(acc, At, Wt, A, W, row0, col0);
    EPILOGUE_IDX
    unsigned short* outs = (unsigned short*)out;
#pragma unroll
    for (int i = 0; i < 4; ++i)
#pragma unroll
        for (int j = 0; j < 4; ++j)
#pragma unroll
            for (int t = 0; t < 4; ++t) {
                int row = row0 + wr + i * 16 + (l >> 4) * 4 + t;
                int c   = col0 + wc + j * 16 + (l & 15);
                float rv = sigm(acc[i][j][t] + bih[512 + c] + bhh[512 + c]);
                float hv = h0[(size_t)row * HD + c];
                outs[(size_t)row * 2560 + 1536 + c] = f2bf(rv * hv);
            }
}

// ----------------------------------------------------------------- gen_zn ---
__global__ __launch_bounds__(256, 2) void k_gen_zn(
    const float* __restrict__ h0,
    const float* __restrict__ wih, const float* __restrict__ bih,
    const float* __restrict__ whh, const float* __restrict__ bhh, float* out) {
    __shared__ alignas(16) char At[16384], Wt[16384];
    const int col0 = (blockIdx.x & 3) * 128;
    const int row0 = (blockIdx.x >> 2) * 128;
    KSrc Az = {{out + 1024, h0 - 128, h0 - 128, h0 - 128, h0 - 128},
               {HD, HD, HD, HD, HD}, {0, 0, 0, 0, 0}, nullptr};
    KSrc Wz = {{wih, whh - 128, whh - 128, whh - 128, whh - 128},
               {128, 512, 512, 512, 512}, {0, 0, 0, 0, 0}, nullptr};
    KSrc An = {{out + 1024, (const unsigned*)out + 704, (const unsigned*)out + 704,
                (const unsigned*)out + 704, (const unsigned*)out + 704},
               {HD, HD, HD, HD, HD}, {0, 1, 1, 1, 1}, nullptr};
    KSrc Wn = {{wih + 1024 * 128, whh + 1024 * 512 - 128, whh + 1024 * 512 - 128,
                whh + 1024 * 512 - 128, whh + 1024 * 512 - 128},
               {128, 512, 512, 512, 512}, {0, 0, 0, 0, 0}, nullptr};
    f32x4 aZ[4][4] = {}, aN[4][4] = {};
    gemm_core<640>(aZ, At, Wt, Az, Wz, row0, col0);
    gemm_core<640>(aN, At, Wt, An, Wn, row0, col0);
    EPILOGUE_IDX
#pragma unroll
    for (int i = 0; i < 4; ++i)
#pragma unroll
        for (int j = 0; j < 4; ++j)
#pragma unroll
            for (int t = 0; t < 4; ++t) {
                int row = row0 + wr + i * 16 + (l >> 4) * 4 + t;
                int c   = col0 + wc + j * 16 + (l & 15);
                float zv = sigm(aZ[i][j][t] + bih[c] + bhh[c]);
                float nv = tanhf(aN[i][j][t] + bih[1024 + c] + bhh[1024 + c]);
                float hv = h0[(size_t)row * HD + c];
                float hp = zv * hv + (1.0f - zv) * nv;
                out[(size_t)row * HD + c] = fminf(fmaxf(hp, -CLIPV), CLIPV);
            }
}

// -------------------------------------------------------------------- fac ---
__global__ __launch_bounds__(256, 2) void k_fac(
    const float* __restrict__ fw, float* out) {
    __shared__ alignas(16) char At[16384], Wt[16384];
    __shared__ float invn[512];
    const int row0 = blockIdx.x * 128;
    const int t = threadIdx.x;
    {
        float s0 = 0.f, s1 = 0.f;
        for (int rr = 0; rr < 128; ++rr) {
            float a0 = fw[rr * 512 + t];
            float a1 = fw[rr * 512 + t + 256];
            s0 = fmaf(a0, a0, s0);
            s1 = fmaf(a1, a1, s1);
        }
        invn[t]       = 1.0f / fmaxf(sqrtf(s0), 1e-12f);
        invn[t + 256] = 1.0f / fmaxf(sqrtf(s1), 1e-12f);
    }
    KSrc A = {{out, out, out, out, nullptr},
              {HD, HD, HD, HD, 0}, {0, 0, 0, 0, 0}, nullptr};
    KSrc W = {{fw, fw, fw, fw, nullptr},
              {512, 512, 512, 512, 0}, {0, 0, 0, 0, 0}, invn};
    f32x4 acc[4][4] = {};
    gemm_core<512>(acc, At, Wt, A, W, row0, 0);
    EPILOGUE_IDX
#pragma unroll
    for (int i = 0; i < 4; ++i)
#pragma unroll
        for (int j = 0; j < 4; ++j)
#pragma unroll
            for (int tt = 0; tt < 4; ++tt) {
                int row = row0 + wr + i * 16 + (l >> 4) * 4 + tt;
                int c   = wc + j * 16 + (l & 15);      // 0..127
                out[(size_t)row * HD + 1152 + c] = acc[i][j][tt];
            }
}

// --------------------------------------------------------------- co_final ---
__global__ __launch_bounds__(256, 2) void k_co_final(
    const float* __restrict__ cw, const float* __restrict__ cb, float* out) {
    __shared__ alignas(16) char At[16384], Wt[16384];
    const int col0 = (blockIdx.x & 1) * 128;
    const int row0 = (blockIdx.x >> 1) * 128;
    KSrc A = {{out + 512, out + 512, nullptr, nullptr, nullptr},
              {HD, HD, 0, 0, 0}, {0, 0, 0, 0, 0}, nullptr};
    KSrc W = {{cw, cw, nullptr, nullptr, nullptr},
              {256, 256, 0, 0, 0}, {0, 0, 0, 0, 0}, nullptr};
    f32x4 acc[4][4] = {};
    gemm_core<256>(acc, At, Wt, A, W, row0, col0);
    EPILOGUE_IDX
#pragma unroll
    for (int i = 0; i < 4; ++i)
#pragma unroll
        for (int j = 0; j < 4; ++j)
#pragma unroll
            for (int t = 0; t < 4; ++t) {
                int row = row0 + wr + i * 16 + (l >> 4) * 4 + t;
                int c   = col0 + wc + j * 16 + (l & 15);   // 0..255
                out[(size_t)row * HD + 768 + c] = acc[i][j][t] + cb[c];
            }
}

// ----------------------------------------------------------------- launch ---
extern "C" void kernel_launch(void* const* d_in, const int* in_sizes, int n_in,
                              void* d_out, int out_size, void* d_ws, size_t ws_size,
                              hipStream_t stream) {
    const float* x        = (const float*)d_in[0];
    const float* h0       = (const float*)d_in[1];
    const float* con_w_ih = (const float*)d_in[2];
    const float* con_b_ih = (const float*)d_in[3];
    const float* con_w_hh = (const float*)d_in[4];
    const float* con_b_hh = (const float*)d_in[5];
    const float* co_w     = (const float*)d_in[6];
    const float* co_b     = (const float*)d_in[7];
    const float* gen_w_ih = (const float*)d_in[8];
    const float* gen_b_ih = (const float*)d_in[9];
    const float* gen_w_hh = (const float*)d_in[10];
    const float* gen_b_hh = (const float*)d_in[11];
    const float* fac_w    = (const float*)d_in[12];
    float* out = (float*)d_out;

    k_con_r   <<<256, 256, 0, stream>>>(x, h0, con_w_ih, con_b_ih, con_w_hh, con_b_hh, out);
    k_con_zn  <<<256, 256, 0, stream>>>(x, h0, con_w_ih, con_b_ih, con_w_hh, con_b_hh, out);
    k_co_gi   <<<128, 256, 0, stream>>>(co_w, co_b, out);
    k_gen_r   <<<512, 256, 0, stream>>>(h0, gen_w_ih, gen_b_ih, gen_w_hh, gen_b_hh, out);
    k_gen_zn  <<<512, 256, 0, stream>>>(h0, gen_w_ih, gen_b_ih, gen_w_hh, gen_b_hh, out);
    k_fac     <<<128, 256, 0, stream>>>(fac_w, out);
    k_co_final<<<256, 256, 0, stream>>>(co_w, co_b, out);
}

// Round 3
// 357.854 us; speedup vs baseline: 6.8952x; 1.2573x over previous
//
#include <hip/hip_runtime.h>
#include <math.h>

// DecoderCell (LFADS) on MI355X — round 3: preconverted bf16 operands in d_ws,
// 2-phase pipelined MFMA GEMM (global_load_lds with pre-swizzled sources).
//
// Stages (stream-serial):
//   pre_h / pre_w / pre_fw : f32 -> bf16 preconversion into d_ws
//   con_zr : z-preact -> out[0:256) f32 ; r*h bf16 -> out f32 [256:384)
//   con_n  : con_state -> out[512:768)
//   co_gi  : gen_input f32 -> out[1024:1152) + bf16 copy -> out f32 [1152:1216)
//   gen_zr : z-preact -> out[0:512) ; r*h bf16 -> out f32 [768:1024)
//   gen_n  : gen_state -> out[0:512)  (reads z-preact same tile first)
//   fac    : factors -> out[1152:1280)
//   co_fin : co_logstd -> out[896:1024) + copy mean [1024:1152)->[768:896)
// Scratch liveness verified: every scratch region is consumed before the
// kernel that finally overwrites it.

#define HD    1280
#define NROW  16384
#define CLIPV 5.0f

typedef float  f32x4  __attribute__((ext_vector_type(4)));
typedef __bf16 bf16x8 __attribute__((ext_vector_type(8)));
typedef short  s16x8  __attribute__((ext_vector_type(8)));

// ws layout (bf16 element offsets)
#define OFF_CW   16777216              // after [16384][1024] h/x panel
#define OFF_CWH  (OFF_CW  + 196608)
#define OFF_COW  (OFF_CWH + 196608)
#define OFF_GWI  (OFF_COW + 65536)
#define OFF_GWH  (OFF_GWI + 196608)
#define OFF_FW   (OFF_GWH + 786432)
#define WS_ELEMS (OFF_FW  + 65536)

__device__ __forceinline__ unsigned short f2bf(float f) {
    unsigned u = __float_as_uint(f);
    u = u + 0x7fffu + ((u >> 16) & 1u);
    return (unsigned short)(u >> 16);
}
__device__ __forceinline__ float sigm(float v) { return 1.0f / (1.0f + __expf(-v)); }

__device__ __forceinline__ void gll16(const void* g, void* l) {
    __builtin_amdgcn_global_load_lds((const __attribute__((address_space(1))) void*)g,
                                     (__attribute__((address_space(3))) void*)l,
                                     16, 0, 0);
}

struct KSrc {                // element(row, kabs) = p[s] + row*ld[s] + kabs ; s = kabs>>7
    const void* p[5];
    int ld[5];
    int kind[5];             // 1 = bf16 (global_load_lds), 0 = f32 (reg-stage + cvt)
    const float* scale;      // per-k scale for f32 chunks (fac fallback only)
};

// ---- staging: issue phase (loads in flight) --------------------------------
__device__ __forceinline__ void stage_issue(char* tile, const KSrc& S, int rbase,
                                            int k0, int sIdx, float* regs) {
    const int tid = threadIdx.x;
    if (S.kind[sIdx]) {
        const char* base = (const char*)S.p[sIdx];
        const int w = tid >> 6;
        const size_t ld = (size_t)S.ld[sIdx];
#pragma unroll
        for (int e = 0; e < 4; ++e) {
            const int q = e * 256 + tid;           // 0..1023 16B slots
            const int r = q >> 3;                  // row 0..127
            const int b = ((q & 7) << 4) ^ ((r & 7) << 4);   // pre-swizzled src byte
            const char* g = base + ((size_t)(rbase + r) * ld + k0) * 2 + b;
            gll16(g, tile + e * 4096 + w * 1024);  // wave-uniform LDS base
        }
    } else {
        const float* base = (const float*)S.p[sIdx];
        const size_t ld = (size_t)S.ld[sIdx];
#pragma unroll
        for (int e = 0; e < 2; ++e) {
            const int q = e * 256 + tid;
            const int r = q >> 2;
            const int kloc = (q & 3) << 4;
            const float* p = base + (size_t)(rbase + r) * ld + k0 + kloc;
            float* d = regs + e * 16;
            *(float4*)(d + 0)  = *(const float4*)(p + 0);
            *(float4*)(d + 4)  = *(const float4*)(p + 4);
            *(float4*)(d + 8)  = *(const float4*)(p + 8);
            *(float4*)(d + 12) = *(const float4*)(p + 12);
        }
    }
}

// ---- staging: write phase (cvt + swizzled ds_write; noop for bf16) ---------
__device__ __forceinline__ void stage_write(char* tile, const KSrc& S, int rbase,
                                            int k0, int sIdx, float* regs) {
    if (S.kind[sIdx]) return;
    const int tid = threadIdx.x;
#pragma unroll
    for (int e = 0; e < 2; ++e) {
        const int q = e * 256 + tid;
        const int r = q >> 2;
        const int kloc = (q & 3) << 4;
        float* ff = regs + e * 16;
        if (S.scale) {
            const int kabs = k0 + kloc;
#pragma unroll
            for (int j = 0; j < 16; ++j) ff[j] *= S.scale[kabs + j];
        }
        s16x8 v0, v1;
#pragma unroll
        for (int j = 0; j < 8; ++j) {
            v0[j] = (short)f2bf(ff[j]);
            v1[j] = (short)f2bf(ff[j + 8]);
        }
        const int swz = (r & 7) << 4;
        *(s16x8*)(tile + r * 128 + ((((q & 3) << 5) + 0)  ^ swz)) = v0;
        *(s16x8*)(tile + r * 128 + ((((q & 3) << 5) + 16) ^ swz)) = v1;
    }
}

__device__ __forceinline__ bf16x8 ldfrag(const char* lds, int r, int ks, int g) {
    const char* p = lds + r * 128 + ((((ks << 2) + g) << 4) ^ ((r & 7) << 4));
    return __builtin_bit_cast(bf16x8, *(const s16x8*)p);
}

__device__ __forceinline__ void compute_tile(f32x4 (&acc)[4][4],
                                             const char* At, const char* Wt) {
    const int l   = threadIdx.x & 63;
    const int w   = threadIdx.x >> 6;
    const int wr  = (w >> 1) << 6;
    const int wc  = (w & 1) << 6;
    const int g   = l >> 4;
    const int r15 = l & 15;
#pragma unroll
    for (int ks = 0; ks < 2; ++ks) {
        bf16x8 a[4], b[4];
#pragma unroll
        for (int f = 0; f < 4; ++f) a[f] = ldfrag(At, wr + f * 16 + r15, ks, g);
#pragma unroll
        for (int f = 0; f < 4; ++f) b[f] = ldfrag(Wt, wc + f * 16 + r15, ks, g);
#pragma unroll
        for (int i = 0; i < 4; ++i)
#pragma unroll
            for (int j = 0; j < 4; ++j)
                acc[i][j] = __builtin_amdgcn_mfma_f32_16x16x32_bf16(a[i], b[j], acc[i][j], 0, 0, 0);
    }
}

// ---- 2-phase double-buffered pipelined GEMM core ---------------------------
template <int NT>
__device__ __forceinline__ void gemm2(f32x4 (&acc)[4][4],
                                      char* A0, char* A1, char* W0, char* W1,
                                      const KSrc& A, const KSrc& W,
                                      int row0, int col0) {
    float ra[32], rw[32];
    stage_issue(A0, A, row0, 0, 0, ra);
    stage_issue(W0, W, col0, 0, 0, rw);
    stage_write(A0, A, row0, 0, 0, ra);
    stage_write(W0, W, col0, 0, 0, rw);
    __syncthreads();
#pragma unroll
    for (int kt = 0; kt < NT; ++kt) {
        char* Ac = (kt & 1) ? A1 : A0;
        char* Wc = (kt & 1) ? W1 : W0;
        char* An = (kt & 1) ? A0 : A1;
        char* Wn = (kt & 1) ? W0 : W1;
        const int sn = (kt + 1) >> 1;
        if (kt + 1 < NT) {
            stage_issue(An, A, row0, (kt + 1) * 64, sn, ra);
            stage_issue(Wn, W, col0, (kt + 1) * 64, sn, rw);
        }
        compute_tile(acc, Ac, Wc);
        if (kt + 1 < NT) {
            stage_write(An, A, row0, (kt + 1) * 64, sn, ra);
            stage_write(Wn, W, col0, (kt + 1) * 64, sn, rw);
            __syncthreads();
        }
    }
}

#define GEMM_SHARED                                                         \
    __shared__ alignas(16) char A0[16384], A1[16384], W0[16384], W1[16384];
#define EPILOGUE_IDX                                                        \
    const int l  = threadIdx.x & 63;                                        \
    const int w  = threadIdx.x >> 6;                                        \
    const int wr = (w >> 1) << 6;                                           \
    const int wc = (w & 1) << 6;

// ---------------------------------------------------------- preconversion ---
__global__ __launch_bounds__(256) void k_pre_h(const float* __restrict__ x,
                                               const float* __restrict__ h0,
                                               unsigned short* __restrict__ wsh) {
#pragma unroll
    for (int e = 0; e < 4; ++e) {
        const int q   = blockIdx.x * 1024 + e * 256 + threadIdx.x;
        const int row = q >> 7;
        const int c8  = (q & 127) << 3;
        const float* src;
        if (c8 < 768)      src = h0 + (size_t)row * HD + c8;
        else if (c8 < 896) src = h0 + (size_t)row * HD + c8 + 384;  // factor
        else               src = x + (size_t)row * 128 + (c8 - 896);
        float4 f0 = *(const float4*)(src + 0);
        float4 f1 = *(const float4*)(src + 4);
        const float ff[8] = {f0.x, f0.y, f0.z, f0.w, f1.x, f1.y, f1.z, f1.w};
        s16x8 v;
#pragma unroll
        for (int j = 0; j < 8; ++j) v[j] = (short)f2bf(ff[j]);
        *(s16x8*)(wsh + (size_t)row * 1024 + c8) = v;
    }
}

__global__ __launch_bounds__(256) void k_pre_w(const float* __restrict__ cw,
                                               const float* __restrict__ cwh,
                                               const float* __restrict__ cow,
                                               const float* __restrict__ gwi,
                                               const float* __restrict__ gwh,
                                               unsigned short* __restrict__ dst) {
    const int q = blockIdx.x * 256 + threadIdx.x;     // 180224 octets exactly
    const size_t eo = (size_t)q * 8;
    const float* src;
    if      (eo < 196608) src = cw  + eo;
    else if (eo < 393216) src = cwh + (eo - 196608);
    else if (eo < 458752) src = cow + (eo - 393216);
    else if (eo < 655360) src = gwi + (eo - 458752);
    else                  src = gwh + (eo - 655360);
    float4 f0 = *(const float4*)(src + 0);
    float4 f1 = *(const float4*)(src + 4);
    const float ff[8] = {f0.x, f0.y, f0.z, f0.w, f1.x, f1.y, f1.z, f1.w};
    s16x8 v;
#pragma unroll
    for (int j = 0; j < 8; ++j) v[j] = (short)f2bf(ff[j]);
    *(s16x8*)(dst + eo) = v;
}

__global__ __launch_bounds__(256) void k_pre_fw(const float* __restrict__ fw,
                                                unsigned short* __restrict__ dst) {
    const int col = blockIdx.x * 256 + threadIdx.x;   // 512 cols
    float s = 0.f;
    for (int r = 0; r < 128; ++r) {
        float a = fw[r * 512 + col];
        s = fmaf(a, a, s);
    }
    const float inv = 1.0f / fmaxf(sqrtf(s), 1e-12f);
    for (int r = 0; r < 128; ++r)
        dst[r * 512 + col] = f2bf(fw[r * 512 + col] * inv);
}

// ----------------------------------------------------------------- con_zr ---
template <bool PRE>
__global__ __launch_bounds__(256, 2) void k_con_zr(
    const float* __restrict__ x, const float* __restrict__ h0,
    const float* __restrict__ wih, const float* __restrict__ bih,
    const float* __restrict__ whh, const float* __restrict__ bhh,
    const unsigned short* __restrict__ ws, float* __restrict__ out) {
    GEMM_SHARED
    const int col0 = (blockIdx.x & 3) * 128;
    const int row0 = (blockIdx.x >> 2) * 128;
    KSrc A, W;
    if (PRE) {
        A = {{ws + 896, ws + 640, ws + 256, ws + 256, nullptr},
             {1024, 1024, 1024, 1024, 0}, {1, 1, 1, 1, 0}, nullptr};
        W = {{ws + OFF_CW, ws + OFF_CW, ws + OFF_CWH - 256, ws + OFF_CWH - 256, nullptr},
             {256, 256, 256, 256, 0}, {1, 1, 1, 1, 0}, nullptr};
    } else {
        A = {{x, h0 + 1152 - 128, h0 + 256, h0 + 256, nullptr},
             {128, HD, HD, HD, 0}, {0, 0, 0, 0, 0}, nullptr};
        W = {{wih, wih, whh - 256, whh - 256, nullptr},
             {256, 256, 256, 256, 0}, {0, 0, 0, 0, 0}, nullptr};
    }
    f32x4 acc[4][4] = {};
    gemm2<8>(acc, A0, A1, W0, W1, A, W, row0, col0);
    EPILOGUE_IDX
    unsigned short* outs = (unsigned short*)out;
    const bool isZ = (col0 < 256);
#pragma unroll
    for (int i = 0; i < 4; ++i)
#pragma unroll
        for (int j = 0; j < 4; ++j)
#pragma unroll
            for (int t = 0; t < 4; ++t) {
                int row = row0 + wr + i * 16 + (l >> 4) * 4 + t;
                int c   = col0 + wc + j * 16 + (l & 15);
                if (isZ) {
                    out[(size_t)row * HD + c] = acc[i][j][t];          // ZP_C
                } else {
                    int c2   = c - 256;
                    float rv = sigm(acc[i][j][t] + bih[256 + c2] + bhh[256 + c2]);
                    float hv = h0[(size_t)row * HD + 512 + c2];
                    outs[(size_t)row * 2560 + 512 + c2] = f2bf(rv * hv); // RH_C
                }
            }
}

// ------------------------------------------------------------------ con_n ---
template <bool PRE>
__global__ __launch_bounds__(256, 2) void k_con_n(
    const float* __restrict__ x, const float* __restrict__ h0,
    const float* __restrict__ wih, const float* __restrict__ bih,
    const float* __restrict__ whh, const float* __restrict__ bhh,
    const unsigned short* __restrict__ ws, float* __restrict__ out) {
    GEMM_SHARED
    const int col0 = (blockIdx.x & 1) * 128;
    const int row0 = (blockIdx.x >> 1) * 128;
    const unsigned short* outs = (const unsigned short*)out;
    KSrc A, W;
    if (PRE) {
        A = {{ws + 896, ws + 640, outs + 256, outs + 256, nullptr},
             {1024, 1024, 2560, 2560, 0}, {1, 1, 1, 1, 0}, nullptr};
        W = {{ws + OFF_CW + 512 * 256, ws + OFF_CW + 512 * 256,
              ws + OFF_CWH + 512 * 256 - 256, ws + OFF_CWH + 512 * 256 - 256, nullptr},
             {256, 256, 256, 256, 0}, {1, 1, 1, 1, 0}, nullptr};
    } else {
        A = {{x, h0 + 1152 - 128, outs + 256, outs + 256, nullptr},
             {128, HD, 2560, 2560, 0}, {0, 0, 1, 1, 0}, nullptr};
        W = {{wih + 512 * 256, wih + 512 * 256,
              whh + 512 * 256 - 256, whh + 512 * 256 - 256, nullptr},
             {256, 256, 256, 256, 0}, {0, 0, 0, 0, 0}, nullptr};
    }
    f32x4 acc[4][4] = {};
    gemm2<8>(acc, A0, A1, W0, W1, A, W, row0, col0);
    EPILOGUE_IDX
#pragma unroll
    for (int i = 0; i < 4; ++i)
#pragma unroll
        for (int j = 0; j < 4; ++j)
#pragma unroll
            for (int t = 0; t < 4; ++t) {
                int row  = row0 + wr + i * 16 + (l >> 4) * 4 + t;
                int c    = col0 + wc + j * 16 + (l & 15);
                float zp = out[(size_t)row * HD + c];                  // ZP_C
                float zv = sigm(zp + bih[c] + bhh[c]);
                float nv = tanhf(acc[i][j][t] + bih[512 + c] + bhh[512 + c]);
                float hv = h0[(size_t)row * HD + 512 + c];
                float hp = zv * hv + (1.0f - zv) * nv;
                out[(size_t)row * HD + 512 + c] = fminf(fmaxf(hp, -CLIPV), CLIPV);
            }
}

// ------------------------------------------------------------------ co_gi ---
template <bool PRE>
__global__ __launch_bounds__(256, 2) void k_co_gi(
    const float* __restrict__ cw, const float* __restrict__ cb,
    const unsigned short* __restrict__ ws, float* __restrict__ out) {
    GEMM_SHARED
    const int row0 = blockIdx.x * 128;
    KSrc A = {{out + 512, out + 512, nullptr, nullptr, nullptr},
              {HD, HD, 0, 0, 0}, {0, 0, 0, 0, 0}, nullptr};
    KSrc W;
    if (PRE) {
        W = {{ws + OFF_COW, ws + OFF_COW, nullptr, nullptr, nullptr},
             {256, 256, 0, 0, 0}, {1, 1, 0, 0, 0}, nullptr};
    } else {
        W = {{cw, cw, nullptr, nullptr, nullptr},
             {256, 256, 0, 0, 0}, {0, 0, 0, 0, 0}, nullptr};
    }
    f32x4 acc[4][4] = {};
    gemm2<4>(acc, A0, A1, W0, W1, A, W, row0, 0);
    EPILOGUE_IDX
    unsigned short* outs = (unsigned short*)out;
#pragma unroll
    for (int i = 0; i < 4; ++i)
#pragma unroll
        for (int j = 0; j < 4; ++j)
#pragma unroll
            for (int t = 0; t < 4; ++t) {
                int row = row0 + wr + i * 16 + (l >> 4) * 4 + t;
                int c   = wc + j * 16 + (l & 15);
                float v = acc[i][j][t] + cb[c];
                out[(size_t)row * HD + 1024 + c]    = v;               // gen_input
                outs[(size_t)row * 2560 + 2304 + c] = f2bf(v);         // GI_B
            }
}

// ----------------------------------------------------------------- gen_zr ---
template <bool PRE>
__global__ __launch_bounds__(256, 2) void k_gen_zr(
    const float* __restrict__ h0,
    const float* __restrict__ wih, const float* __restrict__ bih,
    const float* __restrict__ whh, const float* __restrict__ bhh,
    const unsigned short* __restrict__ ws, float* __restrict__ out) {
    GEMM_SHARED
    const int col0 = (blockIdx.x & 7) * 128;
    const int row0 = (blockIdx.x >> 3) * 128;
    const unsigned short* outs = (const unsigned short*)out;
    KSrc A, W;
    if (PRE) {
        A = {{outs + 2304, ws - 128, ws - 128, ws - 128, ws - 128},
             {2560, 1024, 1024, 1024, 1024}, {1, 1, 1, 1, 1}, nullptr};
        W = {{ws + OFF_GWI, ws + OFF_GWH - 128, ws + OFF_GWH - 128,
              ws + OFF_GWH - 128, ws + OFF_GWH - 128},
             {128, 512, 512, 512, 512}, {1, 1, 1, 1, 1}, nullptr};
    } else {
        A = {{outs + 2304, h0 - 128, h0 - 128, h0 - 128, h0 - 128},
             {2560, HD, HD, HD, HD}, {1, 0, 0, 0, 0}, nullptr};
        W = {{wih, whh - 128, whh - 128, whh - 128, whh - 128},
             {128, 512, 512, 512, 512}, {0, 0, 0, 0, 0}, nullptr};
    }
    f32x4 acc[4][4] = {};
    gemm2<10>(acc, A0, A1, W0, W1, A, W, row0, col0);
    EPILOGUE_IDX
    unsigned short* outw = (unsigned short*)out;
    const bool isZ = (col0 < 512);
#pragma unroll
    for (int i = 0; i < 4; ++i)
#pragma unroll
        for (int j = 0; j < 4; ++j)
#pragma unroll
            for (int t = 0; t < 4; ++t) {
                int row = row0 + wr + i * 16 + (l >> 4) * 4 + t;
                int c   = col0 + wc + j * 16 + (l & 15);
                if (isZ) {
                    out[(size_t)row * HD + c] = acc[i][j][t];          // ZP_G
                } else {
                    int c2   = c - 512;
                    float rv = sigm(acc[i][j][t] + bih[512 + c2] + bhh[512 + c2]);
                    float hv = h0[(size_t)row * HD + c2];
                    outw[(size_t)row * 2560 + 1536 + c2] = f2bf(rv * hv); // RH_G
                }
            }
}

// ------------------------------------------------------------------ gen_n ---
template <bool PRE>
__global__ __launch_bounds__(256, 2) void k_gen_n(
    const float* __restrict__ h0,
    const float* __restrict__ wih, const float* __restrict__ bih,
    const float* __restrict__ whh, const float* __restrict__ bhh,
    const unsigned short* __restrict__ ws, float* __restrict__ out) {
    GEMM_SHARED
    const int col0 = (blockIdx.x & 3) * 128;
    const int row0 = (blockIdx.x >> 2) * 128;
    const unsigned short* outs = (const unsigned short*)out;
    KSrc A = {{outs + 2304, outs + 1408, outs + 1408, outs + 1408, outs + 1408},
              {2560, 2560, 2560, 2560, 2560}, {1, 1, 1, 1, 1}, nullptr};
    KSrc W;
    if (PRE) {
        W = {{ws + OFF_GWI + 1024 * 128, ws + OFF_GWH + 1024 * 512 - 128,
              ws + OFF_GWH + 1024 * 512 - 128, ws + OFF_GWH + 1024 * 512 - 128,
              ws + OFF_GWH + 1024 * 512 - 128},
             {128, 512, 512, 512, 512}, {1, 1, 1, 1, 1}, nullptr};
    } else {
        W = {{wih + 1024 * 128, whh + 1024 * 512 - 128, whh + 1024 * 512 - 128,
              whh + 1024 * 512 - 128, whh + 1024 * 512 - 128},
             {128, 512, 512, 512, 512}, {0, 0, 0, 0, 0}, nullptr};
    }
    f32x4 acc[4][4] = {};
    gemm2<10>(acc, A0, A1, W0, W1, A, W, row0, col0);
    EPILOGUE_IDX
#pragma unroll
    for (int i = 0; i < 4; ++i)
#pragma unroll
        for (int j = 0; j < 4; ++j)
#pragma unroll
            for (int t = 0; t < 4; ++t) {
                int row  = row0 + wr + i * 16 + (l >> 4) * 4 + t;
                int c    = col0 + wc + j * 16 + (l & 15);
                float zp = out[(size_t)row * HD + c];                  // ZP_G
                float zv = sigm(zp + bih[c] + bhh[c]);
                float nv = tanhf(acc[i][j][t] + bih[1024 + c] + bhh[1024 + c]);
                float hv = h0[(size_t)row * HD + c];
                float hp = zv * hv + (1.0f - zv) * nv;
                out[(size_t)row * HD + c] = fminf(fmaxf(hp, -CLIPV), CLIPV);
            }
}

// -------------------------------------------------------------------- fac ---
template <bool PRE>
__global__ __launch_bounds__(256, 2) void k_fac(
    const float* __restrict__ fw,
    const unsigned short* __restrict__ ws, float* __restrict__ out) {
    GEMM_SHARED
    __shared__ float invn[512];
    const int row0 = blockIdx.x * 128;
    if constexpr (!PRE) {
        const int t = threadIdx.x;
        float s0 = 0.f, s1 = 0.f;
        for (int r = 0; r < 128; ++r) {
            float a0 = fw[r * 512 + t];
            float a1 = fw[r * 512 + t + 256];
            s0 = fmaf(a0, a0, s0);
            s1 = fmaf(a1, a1, s1);
        }
        invn[t]       = 1.0f / fmaxf(sqrtf(s0), 1e-12f);
        invn[t + 256] = 1.0f / fmaxf(sqrtf(s1), 1e-12f);
        __syncthreads();
    }
    KSrc A = {{out, out, out, out, nullptr},
              {HD, HD, HD, HD, 0}, {0, 0, 0, 0, 0}, nullptr};
    KSrc W;
    if (PRE) {
        W = {{ws + OFF_FW, ws + OFF_FW, ws + OFF_FW, ws + OFF_FW, nullptr},
             {512, 512, 512, 512, 0}, {1, 1, 1, 1, 0}, nullptr};
    } else {
        W = {{fw, fw, fw, fw, nullptr},
             {512, 512, 512, 512, 0}, {0, 0, 0, 0, 0}, invn};
    }
    f32x4 acc[4][4] = {};
    gemm2<8>(acc, A0, A1, W0, W1, A, W, row0, 0);
    EPILOGUE_IDX
#pragma unroll
    for (int i = 0; i < 4; ++i)
#pragma unroll
        for (int j = 0; j < 4; ++j)
#pragma unroll
            for (int t = 0; t < 4; ++t) {
                int row = row0 + wr + i * 16 + (l >> 4) * 4 + t;
                int c   = wc + j * 16 + (l & 15);
                out[(size_t)row * HD + 1152 + c] = acc[i][j][t];
            }
}

// ----------------------------------------------------------------- co_fin ---
template <bool PRE>
__global__ __launch_bounds__(256, 2) void k_co_fin(
    const float* __restrict__ cw, const float* __restrict__ cb,
    const unsigned short* __restrict__ ws, float* __restrict__ out) {
    GEMM_SHARED
    const int row0 = blockIdx.x * 128;
    KSrc A = {{out + 512, out + 512, nullptr, nullptr, nullptr},
              {HD, HD, 0, 0, 0}, {0, 0, 0, 0, 0}, nullptr};
    KSrc W;
    if (PRE) {
        W = {{ws + OFF_COW + 128 * 256, ws + OFF_COW + 128 * 256, nullptr, nullptr, nullptr},
             {256, 256, 0, 0, 0}, {1, 1, 0, 0, 0}, nullptr};
    } else {
        W = {{cw + 128 * 256, cw + 128 * 256, nullptr, nullptr, nullptr},
             {256, 256, 0, 0, 0}, {0, 0, 0, 0, 0}, nullptr};
    }
    f32x4 acc[4][4] = {};
    gemm2<4>(acc, A0, A1, W0, W1, A, W, row0, 0);
    EPILOGUE_IDX
#pragma unroll
    for (int i = 0; i < 4; ++i)
#pragma unroll
        for (int j = 0; j < 4; ++j)
#pragma unroll
            for (int t = 0; t < 4; ++t) {
                int row = row0 + wr + i * 16 + (l >> 4) * 4 + t;
                int c   = wc + j * 16 + (l & 15);
                out[(size_t)row * HD + 896 + c] = acc[i][j][t] + cb[128 + c]; // logstd
            }
    // copy co_mean from gen_input region into out[768:896)
#pragma unroll
    for (int e = 0; e < 16; ++e) {
        int idx = threadIdx.x + e * 256;          // 4096 float4 units
        int r   = idx >> 5;                       // 128 rows
        int cc  = (idx & 31) << 2;                // 128 cols
        *(float4*)&out[(size_t)(row0 + r) * HD + 768 + cc] =
            *(const float4*)&out[(size_t)(row0 + r) * HD + 1024 + cc];
    }
}

// ----------------------------------------------------------------- launch ---
template <bool PRE>
static void launch_all(const float* x, const float* h0,
                       const float* cwih, const float* cbih,
                       const float* cwhh, const float* cbhh,
                       const float* cow, const float* cob,
                       const float* gwih, const float* gbih,
                       const float* gwhh, const float* gbhh,
                       const float* fw, const unsigned short* ws,
                       float* out, hipStream_t s) {
    k_con_zr<PRE><<<512,  256, 0, s>>>(x, h0, cwih, cbih, cwhh, cbhh, ws, out);
    k_con_n <PRE><<<256,  256, 0, s>>>(x, h0, cwih, cbih, cwhh, cbhh, ws, out);
    k_co_gi <PRE><<<128,  256, 0, s>>>(cow, cob, ws, out);
    k_gen_zr<PRE><<<1024, 256, 0, s>>>(h0, gwih, gbih, gwhh, gbhh, ws, out);
    k_gen_n <PRE><<<512,  256, 0, s>>>(h0, gwih, gbih, gwhh, gbhh, ws, out);
    k_fac   <PRE><<<128,  256, 0, s>>>(fw, ws, out);
    k_co_fin<PRE><<<128,  256, 0, s>>>(cow, cob, ws, out);
}

extern "C" void kernel_launch(void* const* d_in, const int* in_sizes, int n_in,
                              void* d_out, int out_size, void* d_ws, size_t ws_size,
                              hipStream_t stream) {
    const float* x    = (const float*)d_in[0];
    const float* h0   = (const float*)d_in[1];
    const float* cwih = (const float*)d_in[2];
    const float* cbih = (const float*)d_in[3];
    const float* cwhh = (const float*)d_in[4];
    const float* cbhh = (const float*)d_in[5];
    const float* cow  = (const float*)d_in[6];
    const float* cob  = (const float*)d_in[7];
    const float* gwih = (const float*)d_in[8];
    const float* gbih = (const float*)d_in[9];
    const float* gwhh = (const float*)d_in[10];
    const float* gbhh = (const float*)d_in[11];
    const float* fw   = (const float*)d_in[12];
    float* out = (float*)d_out;
    unsigned short* ws = (unsigned short*)d_ws;

    const bool pre = (ws_size >= (size_t)WS_ELEMS * 2);
    if (pre) {
        k_pre_h <<<2048, 256, 0, stream>>>(x, h0, ws);
        k_pre_w <<<704,  256, 0, stream>>>(cwih, cwhh, cow, gwih, gwhh, ws + OFF_CW);
        k_pre_fw<<<2,    256, 0, stream>>>(fw, ws + OFF_FW);
        launch_all<true>(x, h0, cwih, cbih, cwhh, cbhh, cow, cob,
                         gwih, gbih, gwhh, gbhh, fw, ws, out, stream);
    } else {
        launch_all<false>(x, h0, cwih, cbih, cwhh, cbhh, cow, cob,
                          gwih, gbih, gwhh, gbhh, fw, nullptr, out, stream);
    }
}

// Round 4
// 330.595 us; speedup vs baseline: 7.4637x; 1.0825x over previous
//
#include <hip/hip_runtime.h>
#include <math.h>

// DecoderCell (LFADS) on MI355X — round 4: m97-simple single-buffer core
// (32 KB LDS -> 4-5 blocks/CU) + XCD-aware contiguous-chunk block swizzle.
//
// Stages (stream-serial):
//   pre_h / pre_w / pre_fw : f32 -> bf16 preconversion into d_ws
//   con_zr : z-preact -> out[0:256) f32 ; r*h bf16 -> out f32 [256:384)
//   con_n  : con_state -> out[512:768)
//   co_gi  : gen_input f32 -> out[1024:1152) + bf16 copy -> out f32 [1152:1216)
//   gen_zr : z-preact -> out[0:512) ; r*h bf16 -> out f32 [768:1024)
//   gen_n  : gen_state -> out[0:512)
//   fac    : factors -> out[1152:1280)
//   co_fin : co_logstd -> out[896:1024) + copy mean [1024:1152)->[768:896)

#define HD    1280
#define NROW  16384
#define CLIPV 5.0f

typedef float  f32x4  __attribute__((ext_vector_type(4)));
typedef __bf16 bf16x8 __attribute__((ext_vector_type(8)));
typedef short  s16x8  __attribute__((ext_vector_type(8)));

// ws layout (bf16 element offsets)
#define OFF_CW   16777216              // after [16384][1024] h/x panel
#define OFF_CWH  (OFF_CW  + 196608)
#define OFF_COW  (OFF_CWH + 196608)
#define OFF_GWI  (OFF_COW + 65536)
#define OFF_GWH  (OFF_GWI + 196608)
#define OFF_FW   (OFF_GWH + 786432)
#define WS_ELEMS (OFF_FW  + 65536)

__device__ __forceinline__ unsigned short f2bf(float f) {
    unsigned u = __float_as_uint(f);
    u = u + 0x7fffu + ((u >> 16) & 1u);
    return (unsigned short)(u >> 16);
}
__device__ __forceinline__ float sigm(float v) { return 1.0f / (1.0f + __expf(-v)); }

// XCD-aware contiguous-chunk swizzle (T1): XCD k gets logical ids
// [k*nwg/8, (k+1)*nwg/8). Requires gridDim.x % 8 == 0 (all grids comply).
__device__ __forceinline__ int xswz() {
    const int b   = blockIdx.x;
    const int cpx = gridDim.x >> 3;
    return (b & 7) * cpx + (b >> 3);
}

__device__ __forceinline__ void gll16(const void* g, void* l) {
    __builtin_amdgcn_global_load_lds((const __attribute__((address_space(1))) void*)g,
                                     (__attribute__((address_space(3))) void*)l,
                                     16, 0, 0);
}

struct KSrc {                // element(row, kabs) = p[s] + row*ld[s] + kabs ; s = kabs>>7
    const void* p[5];
    int ld[5];
    int kind[5];             // 1 = bf16 (global_load_lds), 0 = f32 (reg-stage + cvt)
    const float* scale;      // per-k scale for f32 chunks (fac fallback only)
};

// ---- staging: issue phase --------------------------------------------------
__device__ __forceinline__ void stage_issue(char* tile, const KSrc& S, int rbase,
                                            int k0, int sIdx, float* regs) {
    const int tid = threadIdx.x;
    if (S.kind[sIdx]) {
        const char* base = (const char*)S.p[sIdx];
        const int w = tid >> 6;
        const size_t ld = (size_t)S.ld[sIdx];
#pragma unroll
        for (int e = 0; e < 4; ++e) {
            const int q = e * 256 + tid;           // 0..1023 16B slots
            const int r = q >> 3;                  // row 0..127
            const int b = ((q & 7) << 4) ^ ((r & 7) << 4);   // pre-swizzled src byte
            const char* g = base + ((size_t)(rbase + r) * ld + k0) * 2 + b;
            gll16(g, tile + e * 4096 + w * 1024);  // wave-uniform LDS base
        }
    } else {
        const float* base = (const float*)S.p[sIdx];
        const size_t ld = (size_t)S.ld[sIdx];
#pragma unroll
        for (int e = 0; e < 2; ++e) {
            const int q = e * 256 + tid;
            const int r = q >> 2;
            const int kloc = (q & 3) << 4;
            const float* p = base + (size_t)(rbase + r) * ld + k0 + kloc;
            float* d = regs + e * 16;
            *(float4*)(d + 0)  = *(const float4*)(p + 0);
            *(float4*)(d + 4)  = *(const float4*)(p + 4);
            *(float4*)(d + 8)  = *(const float4*)(p + 8);
            *(float4*)(d + 12) = *(const float4*)(p + 12);
        }
    }
}

// ---- staging: write phase (cvt + swizzled ds_write; noop for bf16) ---------
__device__ __forceinline__ void stage_write(char* tile, const KSrc& S, int rbase,
                                            int k0, int sIdx, float* regs) {
    if (S.kind[sIdx]) return;
    const int tid = threadIdx.x;
#pragma unroll
    for (int e = 0; e < 2; ++e) {
        const int q = e * 256 + tid;
        const int r = q >> 2;
        const int kloc = (q & 3) << 4;
        float* ff = regs + e * 16;
        if (S.scale) {
            const int kabs = k0 + kloc;
#pragma unroll
            for (int j = 0; j < 16; ++j) ff[j] *= S.scale[kabs + j];
        }
        s16x8 v0, v1;
#pragma unroll
        for (int j = 0; j < 8; ++j) {
            v0[j] = (short)f2bf(ff[j]);
            v1[j] = (short)f2bf(ff[j + 8]);
        }
        const int swz = (r & 7) << 4;
        *(s16x8*)(tile + r * 128 + ((((q & 3) << 5) + 0)  ^ swz)) = v0;
        *(s16x8*)(tile + r * 128 + ((((q & 3) << 5) + 16) ^ swz)) = v1;
    }
}

__device__ __forceinline__ bf16x8 ldfrag(const char* lds, int r, int ks, int g) {
    const char* p = lds + r * 128 + ((((ks << 2) + g) << 4) ^ ((r & 7) << 4));
    return __builtin_bit_cast(bf16x8, *(const s16x8*)p);
}

__device__ __forceinline__ void compute_tile(f32x4 (&acc)[4][4],
                                             const char* At, const char* Wt) {
    const int l   = threadIdx.x & 63;
    const int w   = threadIdx.x >> 6;
    const int wr  = (w >> 1) << 6;
    const int wc  = (w & 1) << 6;
    const int g   = l >> 4;
    const int r15 = l & 15;
#pragma unroll
    for (int ks = 0; ks < 2; ++ks) {
        bf16x8 a[4], b[4];
#pragma unroll
        for (int f = 0; f < 4; ++f) a[f] = ldfrag(At, wr + f * 16 + r15, ks, g);
#pragma unroll
        for (int f = 0; f < 4; ++f) b[f] = ldfrag(Wt, wc + f * 16 + r15, ks, g);
#pragma unroll
        for (int i = 0; i < 4; ++i)
#pragma unroll
            for (int j = 0; j < 4; ++j)
                acc[i][j] = __builtin_amdgcn_mfma_f32_16x16x32_bf16(a[i], b[j], acc[i][j], 0, 0, 0);
    }
}

// ---- single-buffer m97-style GEMM core -------------------------------------
template <int NT>
__device__ __forceinline__ void gemm1(f32x4 (&acc)[4][4], char* At, char* Wt,
                                      const KSrc& A, const KSrc& W,
                                      int row0, int col0) {
    float ra[32], rw[32];
#pragma unroll
    for (int kt = 0; kt < NT; ++kt) {
        const int s = kt >> 1;                     // static chunk index
        if (kt) __syncthreads();                   // LDS reuse guard
        stage_issue(At, A, row0, kt * 64, s, ra);
        stage_issue(Wt, W, col0, kt * 64, s, rw);
        stage_write(At, A, row0, kt * 64, s, ra);
        stage_write(Wt, W, col0, kt * 64, s, rw);
        __syncthreads();
        compute_tile(acc, At, Wt);
    }
}

#define GEMM_SHARED __shared__ alignas(16) char At[16384], Wt[16384];
#define EPILOGUE_IDX                                                        \
    const int l  = threadIdx.x & 63;                                        \
    const int w  = threadIdx.x >> 6;                                        \
    const int wr = (w >> 1) << 6;                                           \
    const int wc = (w & 1) << 6;

// ---------------------------------------------------------- preconversion ---
__global__ __launch_bounds__(256) void k_pre_h(const float* __restrict__ x,
                                               const float* __restrict__ h0,
                                               unsigned short* __restrict__ wsh) {
#pragma unroll
    for (int e = 0; e < 4; ++e) {
        const int q   = blockIdx.x * 1024 + e * 256 + threadIdx.x;
        const int row = q >> 7;
        const int c8  = (q & 127) << 3;
        const float* src;
        if (c8 < 768)      src = h0 + (size_t)row * HD + c8;
        else if (c8 < 896) src = h0 + (size_t)row * HD + c8 + 384;  // factor
        else               src = x + (size_t)row * 128 + (c8 - 896);
        float4 f0 = *(const float4*)(src + 0);
        float4 f1 = *(const float4*)(src + 4);
        const float ff[8] = {f0.x, f0.y, f0.z, f0.w, f1.x, f1.y, f1.z, f1.w};
        s16x8 v;
#pragma unroll
        for (int j = 0; j < 8; ++j) v[j] = (short)f2bf(ff[j]);
        *(s16x8*)(wsh + (size_t)row * 1024 + c8) = v;
    }
}

__global__ __launch_bounds__(256) void k_pre_w(const float* __restrict__ cw,
                                               const float* __restrict__ cwh,
                                               const float* __restrict__ cow,
                                               const float* __restrict__ gwi,
                                               const float* __restrict__ gwh,
                                               unsigned short* __restrict__ dst) {
    const int q = blockIdx.x * 256 + threadIdx.x;     // 180224 octets exactly
    const size_t eo = (size_t)q * 8;
    const float* src;
    if      (eo < 196608) src = cw  + eo;
    else if (eo < 393216) src = cwh + (eo - 196608);
    else if (eo < 458752) src = cow + (eo - 393216);
    else if (eo < 655360) src = gwi + (eo - 458752);
    else                  src = gwh + (eo - 655360);
    float4 f0 = *(const float4*)(src + 0);
    float4 f1 = *(const float4*)(src + 4);
    const float ff[8] = {f0.x, f0.y, f0.z, f0.w, f1.x, f1.y, f1.z, f1.w};
    s16x8 v;
#pragma unroll
    for (int j = 0; j < 8; ++j) v[j] = (short)f2bf(ff[j]);
    *(s16x8*)(dst + eo) = v;
}

__global__ __launch_bounds__(256) void k_pre_fw(const float* __restrict__ fw,
                                                unsigned short* __restrict__ dst) {
    const int col = blockIdx.x * 256 + threadIdx.x;   // 512 cols
    float s = 0.f;
    for (int r = 0; r < 128; ++r) {
        float a = fw[r * 512 + col];
        s = fmaf(a, a, s);
    }
    const float inv = 1.0f / fmaxf(sqrtf(s), 1e-12f);
    for (int r = 0; r < 128; ++r)
        dst[r * 512 + col] = f2bf(fw[r * 512 + col] * inv);
}

// ----------------------------------------------------------------- con_zr ---
template <bool PRE>
__global__ __launch_bounds__(256) void k_con_zr(
    const float* __restrict__ x, const float* __restrict__ h0,
    const float* __restrict__ wih, const float* __restrict__ bih,
    const float* __restrict__ whh, const float* __restrict__ bhh,
    const unsigned short* __restrict__ ws, float* __restrict__ out) {
    GEMM_SHARED
    const int lb   = xswz();
    const int col0 = (lb & 3) * 128;
    const int row0 = (lb >> 2) * 128;
    KSrc A, W;
    if (PRE) {
        A = {{ws + 896, ws + 640, ws + 256, ws + 256, nullptr},
             {1024, 1024, 1024, 1024, 0}, {1, 1, 1, 1, 0}, nullptr};
        W = {{ws + OFF_CW, ws + OFF_CW, ws + OFF_CWH - 256, ws + OFF_CWH - 256, nullptr},
             {256, 256, 256, 256, 0}, {1, 1, 1, 1, 0}, nullptr};
    } else {
        A = {{x, h0 + 1152 - 128, h0 + 256, h0 + 256, nullptr},
             {128, HD, HD, HD, 0}, {0, 0, 0, 0, 0}, nullptr};
        W = {{wih, wih, whh - 256, whh - 256, nullptr},
             {256, 256, 256, 256, 0}, {0, 0, 0, 0, 0}, nullptr};
    }
    f32x4 acc[4][4] = {};
    gemm1<8>(acc, At, Wt, A, W, row0, col0);
    EPILOGUE_IDX
    unsigned short* outs = (unsigned short*)out;
    const bool isZ = (col0 < 256);
#pragma unroll
    for (int i = 0; i < 4; ++i)
#pragma unroll
        for (int j = 0; j < 4; ++j)
#pragma unroll
            for (int t = 0; t < 4; ++t) {
                int row = row0 + wr + i * 16 + (l >> 4) * 4 + t;
                int c   = col0 + wc + j * 16 + (l & 15);
                if (isZ) {
                    out[(size_t)row * HD + c] = acc[i][j][t];          // ZP_C
                } else {
                    int c2   = c - 256;
                    float rv = sigm(acc[i][j][t] + bih[256 + c2] + bhh[256 + c2]);
                    float hv = h0[(size_t)row * HD + 512 + c2];
                    outs[(size_t)row * 2560 + 512 + c2] = f2bf(rv * hv); // RH_C
                }
            }
}

// ------------------------------------------------------------------ con_n ---
template <bool PRE>
__global__ __launch_bounds__(256) void k_con_n(
    const float* __restrict__ x, const float* __restrict__ h0,
    const float* __restrict__ wih, const float* __restrict__ bih,
    const float* __restrict__ whh, const float* __restrict__ bhh,
    const unsigned short* __restrict__ ws, float* __restrict__ out) {
    GEMM_SHARED
    const int lb   = xswz();
    const int col0 = (lb & 1) * 128;
    const int row0 = (lb >> 1) * 128;
    const unsigned short* outs = (const unsigned short*)out;
    KSrc A, W;
    if (PRE) {
        A = {{ws + 896, ws + 640, outs + 256, outs + 256, nullptr},
             {1024, 1024, 2560, 2560, 0}, {1, 1, 1, 1, 0}, nullptr};
        W = {{ws + OFF_CW + 512 * 256, ws + OFF_CW + 512 * 256,
              ws + OFF_CWH + 512 * 256 - 256, ws + OFF_CWH + 512 * 256 - 256, nullptr},
             {256, 256, 256, 256, 0}, {1, 1, 1, 1, 0}, nullptr};
    } else {
        A = {{x, h0 + 1152 - 128, outs + 256, outs + 256, nullptr},
             {128, HD, 2560, 2560, 0}, {0, 0, 1, 1, 0}, nullptr};
        W = {{wih + 512 * 256, wih + 512 * 256,
              whh + 512 * 256 - 256, whh + 512 * 256 - 256, nullptr},
             {256, 256, 256, 256, 0}, {0, 0, 0, 0, 0}, nullptr};
    }
    f32x4 acc[4][4] = {};
    gemm1<8>(acc, At, Wt, A, W, row0, col0);
    EPILOGUE_IDX
#pragma unroll
    for (int i = 0; i < 4; ++i)
#pragma unroll
        for (int j = 0; j < 4; ++j)
#pragma unroll
            for (int t = 0; t < 4; ++t) {
                int row  = row0 + wr + i * 16 + (l >> 4) * 4 + t;
                int c    = col0 + wc + j * 16 + (l & 15);
                float zp = out[(size_t)row * HD + c];                  // ZP_C
                float zv = sigm(zp + bih[c] + bhh[c]);
                float nv = tanhf(acc[i][j][t] + bih[512 + c] + bhh[512 + c]);
                float hv = h0[(size_t)row * HD + 512 + c];
                float hp = zv * hv + (1.0f - zv) * nv;
                out[(size_t)row * HD + 512 + c] = fminf(fmaxf(hp, -CLIPV), CLIPV);
            }
}

// ------------------------------------------------------------------ co_gi ---
template <bool PRE>
__global__ __launch_bounds__(256) void k_co_gi(
    const float* __restrict__ cw, const float* __restrict__ cb,
    const unsigned short* __restrict__ ws, float* __restrict__ out) {
    GEMM_SHARED
    const int row0 = xswz() * 128;
    KSrc A = {{out + 512, out + 512, nullptr, nullptr, nullptr},
              {HD, HD, 0, 0, 0}, {0, 0, 0, 0, 0}, nullptr};
    KSrc W;
    if (PRE) {
        W = {{ws + OFF_COW, ws + OFF_COW, nullptr, nullptr, nullptr},
             {256, 256, 0, 0, 0}, {1, 1, 0, 0, 0}, nullptr};
    } else {
        W = {{cw, cw, nullptr, nullptr, nullptr},
             {256, 256, 0, 0, 0}, {0, 0, 0, 0, 0}, nullptr};
    }
    f32x4 acc[4][4] = {};
    gemm1<4>(acc, At, Wt, A, W, row0, 0);
    EPILOGUE_IDX
    unsigned short* outs = (unsigned short*)out;
#pragma unroll
    for (int i = 0; i < 4; ++i)
#pragma unroll
        for (int j = 0; j < 4; ++j)
#pragma unroll
            for (int t = 0; t < 4; ++t) {
                int row = row0 + wr + i * 16 + (l >> 4) * 4 + t;
                int c   = wc + j * 16 + (l & 15);
                float v = acc[i][j][t] + cb[c];
                out[(size_t)row * HD + 1024 + c]    = v;               // gen_input
                outs[(size_t)row * 2560 + 2304 + c] = f2bf(v);         // GI_B
            }
}

// ----------------------------------------------------------------- gen_zr ---
template <bool PRE>
__global__ __launch_bounds__(256) void k_gen_zr(
    const float* __restrict__ h0,
    const float* __restrict__ wih, const float* __restrict__ bih,
    const float* __restrict__ whh, const float* __restrict__ bhh,
    const unsigned short* __restrict__ ws, float* __restrict__ out) {
    GEMM_SHARED
    const int lb   = xswz();
    const int col0 = (lb & 7) * 128;
    const int row0 = (lb >> 3) * 128;
    const unsigned short* outs = (const unsigned short*)out;
    KSrc A, W;
    if (PRE) {
        A = {{outs + 2304, ws - 128, ws - 128, ws - 128, ws - 128},
             {2560, 1024, 1024, 1024, 1024}, {1, 1, 1, 1, 1}, nullptr};
        W = {{ws + OFF_GWI, ws + OFF_GWH - 128, ws + OFF_GWH - 128,
              ws + OFF_GWH - 128, ws + OFF_GWH - 128},
             {128, 512, 512, 512, 512}, {1, 1, 1, 1, 1}, nullptr};
    } else {
        A = {{outs + 2304, h0 - 128, h0 - 128, h0 - 128, h0 - 128},
             {2560, HD, HD, HD, HD}, {1, 0, 0, 0, 0}, nullptr};
        W = {{wih, whh - 128, whh - 128, whh - 128, whh - 128},
             {128, 512, 512, 512, 512}, {0, 0, 0, 0, 0}, nullptr};
    }
    f32x4 acc[4][4] = {};
    gemm1<10>(acc, At, Wt, A, W, row0, col0);
    EPILOGUE_IDX
    unsigned short* outw = (unsigned short*)out;
    const bool isZ = (col0 < 512);
#pragma unroll
    for (int i = 0; i < 4; ++i)
#pragma unroll
        for (int j = 0; j < 4; ++j)
#pragma unroll
            for (int t = 0; t < 4; ++t) {
                int row = row0 + wr + i * 16 + (l >> 4) * 4 + t;
                int c   = col0 + wc + j * 16 + (l & 15);
                if (isZ) {
                    out[(size_t)row * HD + c] = acc[i][j][t];          // ZP_G
                } else {
                    int c2   = c - 512;
                    float rv = sigm(acc[i][j][t] + bih[512 + c2] + bhh[512 + c2]);
                    float hv = h0[(size_t)row * HD + c2];
                    outw[(size_t)row * 2560 + 1536 + c2] = f2bf(rv * hv); // RH_G
                }
            }
}

// ------------------------------------------------------------------ gen_n ---
template <bool PRE>
__global__ __launch_bounds__(256) void k_gen_n(
    const float* __restrict__ h0,
    const float* __restrict__ wih, const float* __restrict__ bih,
    const float* __restrict__ whh, const float* __restrict__ bhh,
    const unsigned short* __restrict__ ws, float* __restrict__ out) {
    GEMM_SHARED
    const int lb   = xswz();
    const int col0 = (lb & 3) * 128;
    const int row0 = (lb >> 2) * 128;
    const unsigned short* outs = (const unsigned short*)out;
    KSrc A = {{outs + 2304, outs + 1408, outs + 1408, outs + 1408, outs + 1408},
              {2560, 2560, 2560, 2560, 2560}, {1, 1, 1, 1, 1}, nullptr};
    KSrc W;
    if (PRE) {
        W = {{ws + OFF_GWI + 1024 * 128, ws + OFF_GWH + 1024 * 512 - 128,
              ws + OFF_GWH + 1024 * 512 - 128, ws + OFF_GWH + 1024 * 512 - 128,
              ws + OFF_GWH + 1024 * 512 - 128},
             {128, 512, 512, 512, 512}, {1, 1, 1, 1, 1}, nullptr};
    } else {
        W = {{wih + 1024 * 128, whh + 1024 * 512 - 128, whh + 1024 * 512 - 128,
              whh + 1024 * 512 - 128, whh + 1024 * 512 - 128},
             {128, 512, 512, 512, 512}, {0, 0, 0, 0, 0}, nullptr};
    }
    f32x4 acc[4][4] = {};
    gemm1<10>(acc, At, Wt, A, W, row0, col0);
    EPILOGUE_IDX
#pragma unroll
    for (int i = 0; i < 4; ++i)
#pragma unroll
        for (int j = 0; j < 4; ++j)
#pragma unroll
            for (int t = 0; t < 4; ++t) {
                int row  = row0 + wr + i * 16 + (l >> 4) * 4 + t;
                int c    = col0 + wc + j * 16 + (l & 15);
                float zp = out[(size_t)row * HD + c];                  // ZP_G
                float zv = sigm(zp + bih[c] + bhh[c]);
                float nv = tanhf(acc[i][j][t] + bih[1024 + c] + bhh[1024 + c]);
                float hv = h0[(size_t)row * HD + c];
                float hp = zv * hv + (1.0f - zv) * nv;
                out[(size_t)row * HD + c] = fminf(fmaxf(hp, -CLIPV), CLIPV);
            }
}

// -------------------------------------------------------------------- fac ---
template <bool PRE>
__global__ __launch_bounds__(256) void k_fac(
    const float* __restrict__ fw,
    const unsigned short* __restrict__ ws, float* __restrict__ out) {
    GEMM_SHARED
    __shared__ float invn[512];
    const int row0 = xswz() * 128;
    if constexpr (!PRE) {
        const int t = threadIdx.x;
        float s0 = 0.f, s1 = 0.f;
        for (int r = 0; r < 128; ++r) {
            float a0 = fw[r * 512 + t];
            float a1 = fw[r * 512 + t + 256];
            s0 = fmaf(a0, a0, s0);
            s1 = fmaf(a1, a1, s1);
        }
        invn[t]       = 1.0f / fmaxf(sqrtf(s0), 1e-12f);
        invn[t + 256] = 1.0f / fmaxf(sqrtf(s1), 1e-12f);
        __syncthreads();
    }
    KSrc A = {{out, out, out, out, nullptr},
              {HD, HD, HD, HD, 0}, {0, 0, 0, 0, 0}, nullptr};
    KSrc W;
    if (PRE) {
        W = {{ws + OFF_FW, ws + OFF_FW, ws + OFF_FW, ws + OFF_FW, nullptr},
             {512, 512, 512, 512, 0}, {1, 1, 1, 1, 0}, nullptr};
    } else {
        W = {{fw, fw, fw, fw, nullptr},
             {512, 512, 512, 512, 0}, {0, 0, 0, 0, 0}, invn};
    }
    f32x4 acc[4][4] = {};
    gemm1<8>(acc, At, Wt, A, W, row0, 0);
    EPILOGUE_IDX
#pragma unroll
    for (int i = 0; i < 4; ++i)
#pragma unroll
        for (int j = 0; j < 4; ++j)
#pragma unroll
            for (int t = 0; t < 4; ++t) {
                int row = row0 + wr + i * 16 + (l >> 4) * 4 + t;
                int c   = wc + j * 16 + (l & 15);
                out[(size_t)row * HD + 1152 + c] = acc[i][j][t];
            }
}

// ----------------------------------------------------------------- co_fin ---
template <bool PRE>
__global__ __launch_bounds__(256) void k_co_fin(
    const float* __restrict__ cw, const float* __restrict__ cb,
    const unsigned short* __restrict__ ws, float* __restrict__ out) {
    GEMM_SHARED
    const int row0 = xswz() * 128;
    KSrc A = {{out + 512, out + 512, nullptr, nullptr, nullptr},
              {HD, HD, 0, 0, 0}, {0, 0, 0, 0, 0}, nullptr};
    KSrc W;
    if (PRE) {
        W = {{ws + OFF_COW + 128 * 256, ws + OFF_COW + 128 * 256, nullptr, nullptr, nullptr},
             {256, 256, 0, 0, 0}, {1, 1, 0, 0, 0}, nullptr};
    } else {
        W = {{cw + 128 * 256, cw + 128 * 256, nullptr, nullptr, nullptr},
             {256, 256, 0, 0, 0}, {0, 0, 0, 0, 0}, nullptr};
    }
    f32x4 acc[4][4] = {};
    gemm1<4>(acc, At, Wt, A, W, row0, 0);
    EPILOGUE_IDX
#pragma unroll
    for (int i = 0; i < 4; ++i)
#pragma unroll
        for (int j = 0; j < 4; ++j)
#pragma unroll
            for (int t = 0; t < 4; ++t) {
                int row = row0 + wr + i * 16 + (l >> 4) * 4 + t;
                int c   = wc + j * 16 + (l & 15);
                out[(size_t)row * HD + 896 + c] = acc[i][j][t] + cb[128 + c]; // logstd
            }
    // copy co_mean from gen_input region into out[768:896)
#pragma unroll
    for (int e = 0; e < 16; ++e) {
        int idx = threadIdx.x + e * 256;          // 4096 float4 units
        int r   = idx >> 5;                       // 128 rows
        int cc  = (idx & 31) << 2;                // 128 cols
        *(float4*)&out[(size_t)(row0 + r) * HD + 768 + cc] =
            *(const float4*)&out[(size_t)(row0 + r) * HD + 1024 + cc];
    }
}

// ----------------------------------------------------------------- launch ---
template <bool PRE>
static void launch_all(const float* x, const float* h0,
                       const float* cwih, const float* cbih,
                       const float* cwhh, const float* cbhh,
                       const float* cow, const float* cob,
                       const float* gwih, const float* gbih,
                       const float* gwhh, const float* gbhh,
                       const float* fw, const unsigned short* ws,
                       float* out, hipStream_t s) {
    k_con_zr<PRE><<<512,  256, 0, s>>>(x, h0, cwih, cbih, cwhh, cbhh, ws, out);
    k_con_n <PRE><<<256,  256, 0, s>>>(x, h0, cwih, cbih, cwhh, cbhh, ws, out);
    k_co_gi <PRE><<<128,  256, 0, s>>>(cow, cob, ws, out);
    k_gen_zr<PRE><<<1024, 256, 0, s>>>(h0, gwih, gbih, gwhh, gbhh, ws, out);
    k_gen_n <PRE><<<512,  256, 0, s>>>(h0, gwih, gbih, gwhh, gbhh, ws, out);
    k_fac   <PRE><<<128,  256, 0, s>>>(fw, ws, out);
    k_co_fin<PRE><<<128,  256, 0, s>>>(cow, cob, ws, out);
}

extern "C" void kernel_launch(void* const* d_in, const int* in_sizes, int n_in,
                              void* d_out, int out_size, void* d_ws, size_t ws_size,
                              hipStream_t stream) {
    const float* x    = (const float*)d_in[0];
    const float* h0   = (const float*)d_in[1];
    const float* cwih = (const float*)d_in[2];
    const float* cbih = (const float*)d_in[3];
    const float* cwhh = (const float*)d_in[4];
    const float* cbhh = (const float*)d_in[5];
    const float* cow  = (const float*)d_in[6];
    const float* cob  = (const float*)d_in[7];
    const float* gwih = (const float*)d_in[8];
    const float* gbih = (const float*)d_in[9];
    const float* gwhh = (const float*)d_in[10];
    const float* gbhh = (const float*)d_in[11];
    const float* fw   = (const float*)d_in[12];
    float* out = (float*)d_out;
    unsigned short* ws = (unsigned short*)d_ws;

    const bool pre = (ws_size >= (size_t)WS_ELEMS * 2);
    if (pre) {
        k_pre_h <<<2048, 256, 0, stream>>>(x, h0, ws);
        k_pre_w <<<704,  256, 0, stream>>>(cwih, cwhh, cow, gwih, gwhh, ws + OFF_CW);
        k_pre_fw<<<2,    256, 0, stream>>>(fw, ws + OFF_FW);
        launch_all<true>(x, h0, cwih, cbih, cwhh, cbhh, cow, cob,
                         gwih, gbih, gwhh, gbhh, fw, ws, out, stream);
    } else {
        launch_all<false>(x, h0, cwih, cbih, cwhh, cbhh, cow, cob,
                          gwih, gbih, gwhh, gbhh, fw, nullptr, out, stream);
    }
}

// Round 5
// 235.045 us; speedup vs baseline: 10.4979x; 1.4065x over previous
//
#include <hip/hip_runtime.h>
#include <math.h>

// DecoderCell (LFADS) on MI355X — round 5: BM=64 tiles (4 blocks/CU for gen),
// z merged into n kernels (no z-preact round-trip), co mean+logstd merged.
//
// PRE pipeline: pre_h/pre_w/pre_fw -> con_r -> con_zn -> co -> gen_r ->
//               gen_zn -> fac   (9 dispatches)
// Scratch liveness (PRE):
//   rh_C : out f32 [256:384)  (bf16) — written con_r, read con_zn, dead before gen_zn writes [0:512)
//   gi_b : out f32 [1152:1216) (bf16) — written co, read gen_r/gen_zn, dead before fac writes [1152:1280)
//   rh_G : ws panel cols [512:1024) — h_con/factor/x dead after con; written gen_r, read gen_zn
// Every out element is rewritten every call (poison-safe, deterministic).

#define HD    1280
#define NROW  16384
#define CLIPV 5.0f

typedef float  f32x4  __attribute__((ext_vector_type(4)));
typedef __bf16 bf16x8 __attribute__((ext_vector_type(8)));
typedef short  s16x8  __attribute__((ext_vector_type(8)));

// ws layout (bf16 element offsets). Panel: [16384][1024] =
//   cols [0:512) h_gen | [512:768) h_con | [768:896) factor | [896:1024) x
#define OFF_CW   16777216
#define OFF_CWH  (OFF_CW  + 196608)
#define OFF_COW  (OFF_CWH + 196608)
#define OFF_GWI  (OFF_COW + 65536)
#define OFF_GWH  (OFF_GWI + 196608)
#define OFF_FW   (OFF_GWH + 786432)
#define WS_ELEMS (OFF_FW  + 65536)

__device__ __forceinline__ unsigned short f2bf(float f) {
    unsigned u = __float_as_uint(f);
    u = u + 0x7fffu + ((u >> 16) & 1u);
    return (unsigned short)(u >> 16);
}
__device__ __forceinline__ float sigm(float v) { return 1.0f / (1.0f + __expf(-v)); }

// XCD-aware contiguous-chunk swizzle (grids all % 8 == 0)
__device__ __forceinline__ int xswz() {
    const int b   = blockIdx.x;
    const int cpx = gridDim.x >> 3;
    return (b & 7) * cpx + (b >> 3);
}

__device__ __forceinline__ void gll16(const void* g, void* l) {
    __builtin_amdgcn_global_load_lds((const __attribute__((address_space(1))) void*)g,
                                     (__attribute__((address_space(3))) void*)l,
                                     16, 0, 0);
}

struct KSrc {                // element(row, kabs) = p[s] + row*ld[s] + kabs ; s = kabs>>7
    const void* p[5];
    int ld[5];
    int kind[5];             // 1 = bf16 (global_load_lds), 0 = f32 (reg-stage + cvt)
    const float* scale;      // per-k scale for f32 chunks (fac fallback only)
};

// ---- staging: issue phase. R = tile rows (64 for A, 128 for W) -------------
template <int R>
__device__ __forceinline__ void stage_issue(char* tile, const KSrc& S, int rbase,
                                            int k0, int sIdx, float* regs) {
    const int tid = threadIdx.x;
    if (S.kind[sIdx]) {
        const char* base = (const char*)S.p[sIdx];
        const int w = tid >> 6;
        const size_t ld = (size_t)S.ld[sIdx];
#pragma unroll
        for (int e = 0; e < R / 32; ++e) {
            const int q = e * 256 + tid;           // 16B slots
            const int r = q >> 3;                  // row 0..R-1
            const int b = ((q & 7) << 4) ^ ((r & 7) << 4);   // pre-swizzled src byte
            const char* g = base + ((size_t)(rbase + r) * ld + k0) * 2 + b;
            gll16(g, tile + e * 4096 + w * 1024);  // wave-uniform LDS base
        }
    } else {
        const float* base = (const float*)S.p[sIdx];
        const size_t ld = (size_t)S.ld[sIdx];
#pragma unroll
        for (int e = 0; e < R / 64; ++e) {
            const int q = e * 256 + tid;
            const int r = q >> 2;
            const int kloc = (q & 3) << 4;
            const float* p = base + (size_t)(rbase + r) * ld + k0 + kloc;
            float* d = regs + e * 16;
            *(float4*)(d + 0)  = *(const float4*)(p + 0);
            *(float4*)(d + 4)  = *(const float4*)(p + 4);
            *(float4*)(d + 8)  = *(const float4*)(p + 8);
            *(float4*)(d + 12) = *(const float4*)(p + 12);
        }
    }
}

// ---- staging: write phase (cvt + swizzled ds_write; noop for bf16) ---------
template <int R>
__device__ __forceinline__ void stage_write(char* tile, const KSrc& S, int rbase,
                                            int k0, int sIdx, float* regs) {
    if (S.kind[sIdx]) return;
    const int tid = threadIdx.x;
#pragma unroll
    for (int e = 0; e < R / 64; ++e) {
        const int q = e * 256 + tid;
        const int r = q >> 2;
        float* ff = regs + e * 16;
        if (S.scale) {
            const int kabs = k0 + ((q & 3) << 4);
#pragma unroll
            for (int j = 0; j < 16; ++j) ff[j] *= S.scale[kabs + j];
        }
        s16x8 v0, v1;
#pragma unroll
        for (int j = 0; j < 8; ++j) {
            v0[j] = (short)f2bf(ff[j]);
            v1[j] = (short)f2bf(ff[j + 8]);
        }
        const int swz = (r & 7) << 4;
        *(s16x8*)(tile + r * 128 + ((((q & 3) << 5) + 0)  ^ swz)) = v0;
        *(s16x8*)(tile + r * 128 + ((((q & 3) << 5) + 16) ^ swz)) = v1;
    }
}

__device__ __forceinline__ bf16x8 ldfrag(const char* lds, int r, int ks, int g) {
    const char* p = lds + r * 128 + ((((ks << 2) + g) << 4) ^ ((r & 7) << 4));
    return __builtin_bit_cast(bf16x8, *(const s16x8*)p);
}

// per-wave 32 rows x 64 cols ; acc[2][4]
__device__ __forceinline__ void compute_tile64(f32x4 (&acc)[2][4],
                                               const char* At, const char* Wt) {
    const int l   = threadIdx.x & 63;
    const int w   = threadIdx.x >> 6;
    const int wr  = (w >> 1) << 5;
    const int wc  = (w & 1) << 6;
    const int g   = l >> 4;
    const int r15 = l & 15;
#pragma unroll
    for (int ks = 0; ks < 2; ++ks) {
        bf16x8 a[2], b[4];
#pragma unroll
        for (int f = 0; f < 2; ++f) a[f] = ldfrag(At, wr + f * 16 + r15, ks, g);
#pragma unroll
        for (int f = 0; f < 4; ++f) b[f] = ldfrag(Wt, wc + f * 16 + r15, ks, g);
#pragma unroll
        for (int i = 0; i < 2; ++i)
#pragma unroll
            for (int j = 0; j < 4; ++j)
                acc[i][j] = __builtin_amdgcn_mfma_f32_16x16x32_bf16(a[i], b[j], acc[i][j], 0, 0, 0);
    }
}

// ---- single-buffer GEMM core (64x128 tile) ---------------------------------
template <int NT>
__device__ __forceinline__ void gemm1(f32x4 (&acc)[2][4], char* At, char* Wt,
                                      const KSrc& A, const KSrc& W,
                                      int row0, int col0) {
    float ra[16], rw[32];
#pragma unroll
    for (int kt = 0; kt < NT; ++kt) {
        const int s = kt >> 1;                     // static chunk index
        __syncthreads();                           // LDS reuse guard
        stage_issue<64> (At, A, row0, kt * 64, s, ra);
        stage_issue<128>(Wt, W, col0, kt * 64, s, rw);
        stage_write<64> (At, A, row0, kt * 64, s, ra);
        stage_write<128>(Wt, W, col0, kt * 64, s, rw);
        __syncthreads();
        compute_tile64(acc, At, Wt);
    }
}

#define GEMM_SHARED __shared__ alignas(16) char At[8192], Wt[16384];
#define EPILOGUE_IDX                                                        \
    const int l  = threadIdx.x & 63;                                        \
    const int w  = threadIdx.x >> 6;                                        \
    const int wr = (w >> 1) << 5;                                           \
    const int wc = (w & 1) << 6;

// ---------------------------------------------------------- preconversion ---
__global__ __launch_bounds__(256) void k_pre_h(const float* __restrict__ x,
                                               const float* __restrict__ h0,
                                               unsigned short* __restrict__ wsh) {
#pragma unroll
    for (int e = 0; e < 4; ++e) {
        const int q   = blockIdx.x * 1024 + e * 256 + threadIdx.x;
        const int row = q >> 7;
        const int c8  = (q & 127) << 3;
        const float* src;
        if (c8 < 768)      src = h0 + (size_t)row * HD + c8;
        else if (c8 < 896) src = h0 + (size_t)row * HD + c8 + 384;  // factor
        else               src = x + (size_t)row * 128 + (c8 - 896);
        float4 f0 = *(const float4*)(src + 0);
        float4 f1 = *(const float4*)(src + 4);
        const float ff[8] = {f0.x, f0.y, f0.z, f0.w, f1.x, f1.y, f1.z, f1.w};
        s16x8 v;
#pragma unroll
        for (int j = 0; j < 8; ++j) v[j] = (short)f2bf(ff[j]);
        *(s16x8*)(wsh + (size_t)row * 1024 + c8) = v;
    }
}

__global__ __launch_bounds__(256) void k_pre_w(const float* __restrict__ cw,
                                               const float* __restrict__ cwh,
                                               const float* __restrict__ cow,
                                               const float* __restrict__ gwi,
                                               const float* __restrict__ gwh,
                                               unsigned short* __restrict__ dst) {
    const int q = blockIdx.x * 256 + threadIdx.x;     // 180224 octets exactly
    const size_t eo = (size_t)q * 8;
    const float* src;
    if      (eo < 196608) src = cw  + eo;
    else if (eo < 393216) src = cwh + (eo - 196608);
    else if (eo < 458752) src = cow + (eo - 393216);
    else if (eo < 655360) src = gwi + (eo - 458752);
    else                  src = gwh + (eo - 655360);
    float4 f0 = *(const float4*)(src + 0);
    float4 f1 = *(const float4*)(src + 4);
    const float ff[8] = {f0.x, f0.y, f0.z, f0.w, f1.x, f1.y, f1.z, f1.w};
    s16x8 v;
#pragma unroll
    for (int j = 0; j < 8; ++j) v[j] = (short)f2bf(ff[j]);
    *(s16x8*)(dst + eo) = v;
}

__global__ __launch_bounds__(256) void k_pre_fw(const float* __restrict__ fw,
                                                unsigned short* __restrict__ dst) {
    const int col = blockIdx.x * 256 + threadIdx.x;   // 512 cols
    float s = 0.f;
    for (int r = 0; r < 128; ++r) {
        float a = fw[r * 512 + col];
        s = fmaf(a, a, s);
    }
    const float inv = 1.0f / fmaxf(sqrtf(s), 1e-12f);
    for (int r = 0; r < 128; ++r)
        dst[r * 512 + col] = f2bf(fw[r * 512 + col] * inv);
}

// ------------------------------------------------------------------ con_r ---
template <bool PRE>
__global__ __launch_bounds__(256) void k_con_r(
    const float* __restrict__ x, const float* __restrict__ h0,
    const float* __restrict__ wih, const float* __restrict__ bih,
    const float* __restrict__ whh, const float* __restrict__ bhh,
    const unsigned short* __restrict__ ws, float* __restrict__ out) {
    GEMM_SHARED
    const int lb   = xswz();
    const int col0 = (lb & 1) * 128;                 // r cols 0..255
    const int row0 = (lb >> 1) * 64;
    KSrc A, W;
    if (PRE) {
        A = {{ws + 896, ws + 640, ws + 256, ws + 256, nullptr},
             {1024, 1024, 1024, 1024, 0}, {1, 1, 1, 1, 0}, nullptr};
        W = {{ws + OFF_CW + 65536, ws + OFF_CW + 65536,
              ws + OFF_CWH + 65536 - 256, ws + OFF_CWH + 65536 - 256, nullptr},
             {256, 256, 256, 256, 0}, {1, 1, 1, 1, 0}, nullptr};
    } else {
        A = {{x, h0 + 1024, h0 + 256, h0 + 256, nullptr},
             {128, HD, HD, HD, 0}, {0, 0, 0, 0, 0}, nullptr};
        W = {{wih + 65536, wih + 65536, whh + 65536 - 256, whh + 65536 - 256, nullptr},
             {256, 256, 256, 256, 0}, {0, 0, 0, 0, 0}, nullptr};
    }
    f32x4 acc[2][4] = {};
    gemm1<8>(acc, At, Wt, A, W, row0, col0);
    EPILOGUE_IDX
    unsigned short* outs = (unsigned short*)out;
#pragma unroll
    for (int i = 0; i < 2; ++i)
#pragma unroll
        for (int j = 0; j < 4; ++j)
#pragma unroll
            for (int t = 0; t < 4; ++t) {
                int row = row0 + wr + i * 16 + (l >> 4) * 4 + t;
                int c   = col0 + wc + j * 16 + (l & 15);
                float rv = sigm(acc[i][j][t] + bih[256 + c] + bhh[256 + c]);
                float hv = h0[(size_t)row * HD + 512 + c];
                outs[(size_t)row * 2560 + 512 + c] = f2bf(rv * hv);    // rh_C
            }
}

// ----------------------------------------------------------------- con_zn ---
template <bool PRE>
__global__ __launch_bounds__(256) void k_con_zn(
    const float* __restrict__ x, const float* __restrict__ h0,
    const float* __restrict__ wih, const float* __restrict__ bih,
    const float* __restrict__ whh, const float* __restrict__ bhh,
    const unsigned short* __restrict__ ws, float* __restrict__ out) {
    GEMM_SHARED
    const int lb   = xswz();
    const int col0 = (lb & 1) * 128;
    const int row0 = (lb >> 1) * 64;
    const unsigned short* outs = (const unsigned short*)out;
    KSrc Az, Wz, An, Wn;
    if (PRE) {
        Az = {{ws + 896, ws + 640, ws + 256, ws + 256, nullptr},
              {1024, 1024, 1024, 1024, 0}, {1, 1, 1, 1, 0}, nullptr};
        Wz = {{ws + OFF_CW, ws + OFF_CW, ws + OFF_CWH - 256, ws + OFF_CWH - 256, nullptr},
              {256, 256, 256, 256, 0}, {1, 1, 1, 1, 0}, nullptr};
        An = {{ws + 896, ws + 640, outs + 256, outs + 256, nullptr},
              {1024, 1024, 2560, 2560, 0}, {1, 1, 1, 1, 0}, nullptr};
        Wn = {{ws + OFF_CW + 512 * 256, ws + OFF_CW + 512 * 256,
               ws + OFF_CWH + 512 * 256 - 256, ws + OFF_CWH + 512 * 256 - 256, nullptr},
              {256, 256, 256, 256, 0}, {1, 1, 1, 1, 0}, nullptr};
    } else {
        Az = {{x, h0 + 1024, h0 + 256, h0 + 256, nullptr},
              {128, HD, HD, HD, 0}, {0, 0, 0, 0, 0}, nullptr};
        Wz = {{wih, wih, whh - 256, whh - 256, nullptr},
              {256, 256, 256, 256, 0}, {0, 0, 0, 0, 0}, nullptr};
        An = {{x, h0 + 1024, outs + 256, outs + 256, nullptr},
              {128, HD, 2560, 2560, 0}, {0, 0, 1, 1, 0}, nullptr};
        Wn = {{wih + 512 * 256, wih + 512 * 256,
               whh + 512 * 256 - 256, whh + 512 * 256 - 256, nullptr},
              {256, 256, 256, 256, 0}, {0, 0, 0, 0, 0}, nullptr};
    }
    f32x4 aZ[2][4] = {}, aN[2][4] = {};
    gemm1<8>(aZ, At, Wt, Az, Wz, row0, col0);
    gemm1<8>(aN, At, Wt, An, Wn, row0, col0);
    EPILOGUE_IDX
#pragma unroll
    for (int i = 0; i < 2; ++i)
#pragma unroll
        for (int j = 0; j < 4; ++j)
#pragma unroll
            for (int t = 0; t < 4; ++t) {
                int row = row0 + wr + i * 16 + (l >> 4) * 4 + t;
                int c   = col0 + wc + j * 16 + (l & 15);
                float zv = sigm(aZ[i][j][t] + bih[c] + bhh[c]);
                float nv = tanhf(aN[i][j][t] + bih[512 + c] + bhh[512 + c]);
                float hv = h0[(size_t)row * HD + 512 + c];
                float hp = zv * hv + (1.0f - zv) * nv;
                out[(size_t)row * HD + 512 + c] = fminf(fmaxf(hp, -CLIPV), CLIPV);
            }
}

// --------------------------------------------------------------------- co ---
// PRE: full N=256 (mean -> [768) + gi[1024) + gi_b ; logstd -> [896)).
// !PRE: writes gi + gi_b only (logstd handled by co_fin).
template <bool PRE>
__global__ __launch_bounds__(256) void k_co(
    const float* __restrict__ cw, const float* __restrict__ cb,
    const unsigned short* __restrict__ ws, float* __restrict__ out) {
    GEMM_SHARED
    const int lb   = xswz();
    const int col0 = (lb & 1) * 128;
    const int row0 = (lb >> 1) * 64;
    KSrc A = {{out + 512, out + 512, nullptr, nullptr, nullptr},
              {HD, HD, 0, 0, 0}, {0, 0, 0, 0, 0}, nullptr};
    KSrc W;
    if (PRE) {
        W = {{ws + OFF_COW, ws + OFF_COW, nullptr, nullptr, nullptr},
             {256, 256, 0, 0, 0}, {1, 1, 0, 0, 0}, nullptr};
    } else {
        W = {{cw, cw, nullptr, nullptr, nullptr},
             {256, 256, 0, 0, 0}, {0, 0, 0, 0, 0}, nullptr};
    }
    f32x4 acc[2][4] = {};
    gemm1<4>(acc, At, Wt, A, W, row0, col0);
    EPILOGUE_IDX
    unsigned short* outs = (unsigned short*)out;
#pragma unroll
    for (int i = 0; i < 2; ++i)
#pragma unroll
        for (int j = 0; j < 4; ++j)
#pragma unroll
            for (int t = 0; t < 4; ++t) {
                int row = row0 + wr + i * 16 + (l >> 4) * 4 + t;
                int c   = col0 + wc + j * 16 + (l & 15);
                float v = acc[i][j][t] + cb[c];
                if (c < 128) {                         // co_mean
                    out[(size_t)row * HD + 1024 + c]    = v;           // gen_input
                    outs[(size_t)row * 2560 + 2304 + c] = f2bf(v);     // gi_b
                    if (PRE) out[(size_t)row * HD + 768 + c] = v;      // mean out
                } else if (PRE) {
                    out[(size_t)row * HD + 896 + (c - 128)] = v;       // logstd
                }
            }
}

// ------------------------------------------------------------------ gen_r ---
template <bool PRE>
__global__ __launch_bounds__(256) void k_gen_r(
    const float* __restrict__ h0,
    const float* __restrict__ wih, const float* __restrict__ bih,
    const float* __restrict__ whh, const float* __restrict__ bhh,
    unsigned short* __restrict__ ws, float* __restrict__ out) {
    GEMM_SHARED
    const int lb   = xswz();
    const int col0 = (lb & 3) * 128;
    const int row0 = (lb >> 2) * 64;
    const unsigned short* outs = (const unsigned short*)out;
    KSrc A, W;
    if (PRE) {
        A = {{outs + 2304, ws - 128, ws - 128, ws - 128, ws - 128},
             {2560, 1024, 1024, 1024, 1024}, {1, 1, 1, 1, 1}, nullptr};
        W = {{ws + OFF_GWI + 65536, ws + OFF_GWH + 512 * 512 - 128,
              ws + OFF_GWH + 512 * 512 - 128, ws + OFF_GWH + 512 * 512 - 128,
              ws + OFF_GWH + 512 * 512 - 128},
             {128, 512, 512, 512, 512}, {1, 1, 1, 1, 1}, nullptr};
    } else {
        A = {{outs + 2304, h0 - 128, h0 - 128, h0 - 128, h0 - 128},
             {2560, HD, HD, HD, HD}, {1, 0, 0, 0, 0}, nullptr};
        W = {{wih + 65536, whh + 512 * 512 - 128, whh + 512 * 512 - 128,
              whh + 512 * 512 - 128, whh + 512 * 512 - 128},
             {128, 512, 512, 512, 512}, {0, 0, 0, 0, 0}, nullptr};
    }
    f32x4 acc[2][4] = {};
    gemm1<10>(acc, At, Wt, A, W, row0, col0);
    EPILOGUE_IDX
    unsigned short* outw = (unsigned short*)out;
#pragma unroll
    for (int i = 0; i < 2; ++i)
#pragma unroll
        for (int j = 0; j < 4; ++j)
#pragma unroll
            for (int t = 0; t < 4; ++t) {
                int row = row0 + wr + i * 16 + (l >> 4) * 4 + t;
                int c   = col0 + wc + j * 16 + (l & 15);
                float rv = sigm(acc[i][j][t] + bih[512 + c] + bhh[512 + c]);
                float hv = h0[(size_t)row * HD + c];
                unsigned short rh = f2bf(rv * hv);
                if (PRE) ws  [(size_t)row * 1024 + 512 + c]  = rh;     // rh_G (panel)
                else     outw[(size_t)row * 2560 + 1536 + c] = rh;     // rh_G (out)
            }
}

// ----------------------------------------------------------------- gen_zn ---
template <bool PRE>
__global__ __launch_bounds__(256) void k_gen_zn(
    const float* __restrict__ h0,
    const float* __restrict__ wih, const float* __restrict__ bih,
    const float* __restrict__ whh, const float* __restrict__ bhh,
    const unsigned short* __restrict__ ws, float* __restrict__ out) {
    GEMM_SHARED
    const int lb   = xswz();
    const int col0 = (lb & 3) * 128;
    const int row0 = (lb >> 2) * 64;
    const unsigned short* outs = (const unsigned short*)out;
    KSrc Az, Wz, An, Wn;
    if (PRE) {
        Az = {{outs + 2304, ws - 128, ws - 128, ws - 128, ws - 128},
              {2560, 1024, 1024, 1024, 1024}, {1, 1, 1, 1, 1}, nullptr};
        Wz = {{ws + OFF_GWI, ws + OFF_GWH - 128, ws + OFF_GWH - 128,
               ws + OFF_GWH - 128, ws + OFF_GWH - 128},
              {128, 512, 512, 512, 512}, {1, 1, 1, 1, 1}, nullptr};
        An = {{outs + 2304, ws + 384, ws + 384, ws + 384, ws + 384},
              {2560, 1024, 1024, 1024, 1024}, {1, 1, 1, 1, 1}, nullptr};
        Wn = {{ws + OFF_GWI + 1024 * 128, ws + OFF_GWH + 1024 * 512 - 128,
               ws + OFF_GWH + 1024 * 512 - 128, ws + OFF_GWH + 1024 * 512 - 128,
               ws + OFF_GWH + 1024 * 512 - 128},
              {128, 512, 512, 512, 512}, {1, 1, 1, 1, 1}, nullptr};
    } else {
        Az = {{outs + 2304, h0 - 128, h0 - 128, h0 - 128, h0 - 128},
              {2560, HD, HD, HD, HD}, {1, 0, 0, 0, 0}, nullptr};
        Wz = {{wih, whh - 128, whh - 128, whh - 128, whh - 128},
              {128, 512, 512, 512, 512}, {0, 0, 0, 0, 0}, nullptr};
        An = {{outs + 2304, outs + 1408, outs + 1408, outs + 1408, outs + 1408},
              {2560, 2560, 2560, 2560, 2560}, {1, 1, 1, 1, 1}, nullptr};
        Wn = {{wih + 1024 * 128, whh + 1024 * 512 - 128, whh + 1024 * 512 - 128,
               whh + 1024 * 512 - 128, whh + 1024 * 512 - 128},
              {128, 512, 512, 512, 512}, {0, 0, 0, 0, 0}, nullptr};
    }
    f32x4 aZ[2][4] = {}, aN[2][4] = {};
    gemm1<10>(aZ, At, Wt, Az, Wz, row0, col0);
    gemm1<10>(aN, At, Wt, An, Wn, row0, col0);
    EPILOGUE_IDX
#pragma unroll
    for (int i = 0; i < 2; ++i)
#pragma unroll
        for (int j = 0; j < 4; ++j)
#pragma unroll
            for (int t = 0; t < 4; ++t) {
                int row = row0 + wr + i * 16 + (l >> 4) * 4 + t;
                int c   = col0 + wc + j * 16 + (l & 15);
                float zv = sigm(aZ[i][j][t] + bih[c] + bhh[c]);
                float nv = tanhf(aN[i][j][t] + bih[1024 + c] + bhh[1024 + c]);
                float hv = h0[(size_t)row * HD + c];
                float hp = zv * hv + (1.0f - zv) * nv;
                out[(size_t)row * HD + c] = fminf(fmaxf(hp, -CLIPV), CLIPV);
            }
}

// -------------------------------------------------------------------- fac ---
template <bool PRE>
__global__ __launch_bounds__(256) void k_fac(
    const float* __restrict__ fw,
    const unsigned short* __restrict__ ws, float* __restrict__ out) {
    GEMM_SHARED
    __shared__ float invn[512];
    const int row0 = xswz() * 64;
    if constexpr (!PRE) {
        const int t = threadIdx.x;
        float s0 = 0.f, s1 = 0.f;
        for (int r = 0; r < 128; ++r) {
            float a0 = fw[r * 512 + t];
            float a1 = fw[r * 512 + t + 256];
            s0 = fmaf(a0, a0, s0);
            s1 = fmaf(a1, a1, s1);
        }
        invn[t]       = 1.0f / fmaxf(sqrtf(s0), 1e-12f);
        invn[t + 256] = 1.0f / fmaxf(sqrtf(s1), 1e-12f);
        __syncthreads();
    }
    KSrc A = {{out, out, out, out, nullptr},
              {HD, HD, HD, HD, 0}, {0, 0, 0, 0, 0}, nullptr};
    KSrc W;
    if (PRE) {
        W = {{ws + OFF_FW, ws + OFF_FW, ws + OFF_FW, ws + OFF_FW, nullptr},
             {512, 512, 512, 512, 0}, {1, 1, 1, 1, 0}, nullptr};
    } else {
        W = {{fw, fw, fw, fw, nullptr},
             {512, 512, 512, 512, 0}, {0, 0, 0, 0, 0}, invn};
    }
    f32x4 acc[2][4] = {};
    gemm1<8>(acc, At, Wt, A, W, row0, 0);
    EPILOGUE_IDX
#pragma unroll
    for (int i = 0; i < 2; ++i)
#pragma unroll
        for (int j = 0; j < 4; ++j)
#pragma unroll
            for (int t = 0; t < 4; ++t) {
                int row = row0 + wr + i * 16 + (l >> 4) * 4 + t;
                int c   = wc + j * 16 + (l & 15);
                out[(size_t)row * HD + 1152 + c] = acc[i][j][t];
            }
}

// --------------------------------------------------- co_fin (fallback only) --
__global__ __launch_bounds__(256) void k_co_fin(
    const float* __restrict__ cw, const float* __restrict__ cb,
    float* __restrict__ out) {
    GEMM_SHARED
    const int row0 = xswz() * 64;
    KSrc A = {{out + 512, out + 512, nullptr, nullptr, nullptr},
              {HD, HD, 0, 0, 0}, {0, 0, 0, 0, 0}, nullptr};
    KSrc W = {{cw + 128 * 256, cw + 128 * 256, nullptr, nullptr, nullptr},
              {256, 256, 0, 0, 0}, {0, 0, 0, 0, 0}, nullptr};
    f32x4 acc[2][4] = {};
    gemm1<4>(acc, At, Wt, A, W, row0, 0);
    EPILOGUE_IDX
#pragma unroll
    for (int i = 0; i < 2; ++i)
#pragma unroll
        for (int j = 0; j < 4; ++j)
#pragma unroll
            for (int t = 0; t < 4; ++t) {
                int row = row0 + wr + i * 16 + (l >> 4) * 4 + t;
                int c   = wc + j * 16 + (l & 15);
                out[(size_t)row * HD + 896 + c] = acc[i][j][t] + cb[128 + c];
            }
    // copy co_mean from gen_input region into out[768:896)
#pragma unroll
    for (int e = 0; e < 8; ++e) {
        int idx = threadIdx.x + e * 256;          // 2048 float4 units
        int r   = idx >> 5;                       // 64 rows
        int cc  = (idx & 31) << 2;                // 128 cols
        *(float4*)&out[(size_t)(row0 + r) * HD + 768 + cc] =
            *(const float4*)&out[(size_t)(row0 + r) * HD + 1024 + cc];
    }
}

// ----------------------------------------------------------------- launch ---
extern "C" void kernel_launch(void* const* d_in, const int* in_sizes, int n_in,
                              void* d_out, int out_size, void* d_ws, size_t ws_size,
                              hipStream_t stream) {
    const float* x    = (const float*)d_in[0];
    const float* h0   = (const float*)d_in[1];
    const float* cwih = (const float*)d_in[2];
    const float* cbih = (const float*)d_in[3];
    const float* cwhh = (const float*)d_in[4];
    const float* cbhh = (const float*)d_in[5];
    const float* cow  = (const float*)d_in[6];
    const float* cob  = (const float*)d_in[7];
    const float* gwih = (const float*)d_in[8];
    const float* gbih = (const float*)d_in[9];
    const float* gwhh = (const float*)d_in[10];
    const float* gbhh = (const float*)d_in[11];
    const float* fw   = (const float*)d_in[12];
    float* out = (float*)d_out;
    unsigned short* ws = (unsigned short*)d_ws;

    const bool pre = (ws_size >= (size_t)WS_ELEMS * 2);
    if (pre) {
        k_pre_h <<<2048, 256, 0, stream>>>(x, h0, ws);
        k_pre_w <<<704,  256, 0, stream>>>(cwih, cwhh, cow, gwih, gwhh, ws + OFF_CW);
        k_pre_fw<<<2,    256, 0, stream>>>(fw, ws + OFF_FW);
        k_con_r <true><<<512,  256, 0, stream>>>(x, h0, cwih, cbih, cwhh, cbhh, ws, out);
        k_con_zn<true><<<512,  256, 0, stream>>>(x, h0, cwih, cbih, cwhh, cbhh, ws, out);
        k_co    <true><<<512,  256, 0, stream>>>(cow, cob, ws, out);
        k_gen_r <true><<<1024, 256, 0, stream>>>(h0, gwih, gbih, gwhh, gbhh, ws, out);
        k_gen_zn<true><<<1024, 256, 0, stream>>>(h0, gwih, gbih, gwhh, gbhh, ws, out);
        k_fac   <true><<<256,  256, 0, stream>>>(fw, ws, out);
    } else {
        k_con_r <false><<<512,  256, 0, stream>>>(x, h0, cwih, cbih, cwhh, cbhh, nullptr, out);
        k_con_zn<false><<<512,  256, 0, stream>>>(x, h0, cwih, cbih, cwhh, cbhh, nullptr, out);
        k_co    <false><<<512,  256, 0, stream>>>(cow, cob, nullptr, out);
        k_gen_r <false><<<1024, 256, 0, stream>>>(h0, gwih, gbih, gwhh, gbhh, nullptr, out);
        k_gen_zn<false><<<1024, 256, 0, stream>>>(h0, gwih, gbih, gwhh, gbhh, nullptr, out);
        k_fac   <false><<<256,  256, 0, stream>>>(fw, nullptr, out);
        k_co_fin<<<256, 256, 0, stream>>>(cow, cob, out);
    }
}

// Round 6
// 216.205 us; speedup vs baseline: 11.4127x; 1.0871x over previous
//
#include <hip/hip_runtime.h>
#include <math.h>

// DecoderCell (LFADS) on MI355X — round 6: counted-vmcnt double-buffered
// 2-phase pipeline (T3/T4) for all large GEMMs; z+n fused in one pipeline.
//
// PRE pipeline: pre_h/pre_w/pre_fw -> con_r -> con_zn -> co -> gen_r ->
//               gen_zn -> fac   (9 dispatches)
// Scratch liveness (PRE):
//   rh_C   : out f32 [256:384) (bf16) — con_r -> con_zn, dead before gen_zn
//   cs_b   : out f32 [384:512) (bf16 con_state) — con_zn -> co, dead before gen_zn
//   gi_b   : out f32 [1152:1216) (bf16) — co -> gen_r/gen_zn, dead before fac
//   rh_G   : ws panel cols [512:1024) — gen_r -> gen_zn
// Every out element rewritten every call (poison-safe, deterministic).

#define HD    1280
#define NROW  16384
#define CLIPV 5.0f

typedef float  f32x4  __attribute__((ext_vector_type(4)));
typedef __bf16 bf16x8 __attribute__((ext_vector_type(8)));
typedef short  s16x8  __attribute__((ext_vector_type(8)));

// ws layout (bf16 element offsets). Panel: [16384][1024] =
//   cols [0:512) h_gen | [512:768) h_con | [768:896) factor | [896:1024) x
#define OFF_CW   16777216
#define OFF_CWH  (OFF_CW  + 196608)
#define OFF_COW  (OFF_CWH + 196608)
#define OFF_GWI  (OFF_COW + 65536)
#define OFF_GWH  (OFF_GWI + 196608)
#define OFF_FW   (OFF_GWH + 786432)
#define WS_ELEMS (OFF_FW  + 65536)

__device__ __forceinline__ unsigned short f2bf(float f) {
    unsigned u = __float_as_uint(f);
    u = u + 0x7fffu + ((u >> 16) & 1u);
    return (unsigned short)(u >> 16);
}
__device__ __forceinline__ float sigm(float v) { return 1.0f / (1.0f + __expf(-v)); }

// XCD-aware contiguous-chunk swizzle (grids all % 8 == 0)
__device__ __forceinline__ int xswz() {
    const int b   = blockIdx.x;
    const int cpx = gridDim.x >> 3;
    return (b & 7) * cpx + (b >> 3);
}

__device__ __forceinline__ void gll16(const void* g, void* l) {
    __builtin_amdgcn_global_load_lds((const __attribute__((address_space(1))) void*)g,
                                     (__attribute__((address_space(3))) void*)l,
                                     16, 0, 0);
}

struct KSrc {                // element(row, kabs) = p[s] + row*ld[s] + kabs ; s = kabs>>7
    const void* p[5];
    int ld[5];
    int kind[5];             // 1 = bf16 (global_load_lds), 0 = f32 (reg-stage + cvt)
    const float* scale;
};

// ---- bf16 staging for the pipelined core: R rows x 64 k, pre-swizzled src --
template <int R>
__device__ __forceinline__ void stage_b(char* tile, const void* p, int ld,
                                        int rbase, int k0) {
    const char* base = (const char*)p;
    const int tid = threadIdx.x;
    const int w   = tid >> 6;
#pragma unroll
    for (int e = 0; e < R / 32; ++e) {
        const int q = e * 256 + tid;               // 16B slots
        const int r = q >> 3;
        const int b = ((q & 7) << 4) ^ ((r & 7) << 4);
        const char* g = base + ((size_t)(rbase + r) * (size_t)ld + k0) * 2 + b;
        gll16(g, tile + e * 4096 + w * 1024);      // wave-uniform LDS base
    }
}

// ---- legacy staging (fallback path + fac/co_fin) ---------------------------
template <int R>
__device__ __forceinline__ void stage_issue(char* tile, const KSrc& S, int rbase,
                                            int k0, int sIdx, float* regs) {
    const int tid = threadIdx.x;
    if (S.kind[sIdx]) {
        stage_b<R>(tile, S.p[sIdx], S.ld[sIdx], rbase, k0);
    } else {
        const float* base = (const float*)S.p[sIdx];
        const size_t ld = (size_t)S.ld[sIdx];
#pragma unroll
        for (int e = 0; e < R / 64; ++e) {
            const int q = e * 256 + tid;
            const int r = q >> 2;
            const int kloc = (q & 3) << 4;
            const float* pp = base + (size_t)(rbase + r) * ld + k0 + kloc;
            float* d = regs + e * 16;
            *(float4*)(d + 0)  = *(const float4*)(pp + 0);
            *(float4*)(d + 4)  = *(const float4*)(pp + 4);
            *(float4*)(d + 8)  = *(const float4*)(pp + 8);
            *(float4*)(d + 12) = *(const float4*)(pp + 12);
        }
    }
}

template <int R>
__device__ __forceinline__ void stage_write(char* tile, const KSrc& S, int rbase,
                                            int k0, int sIdx, float* regs) {
    if (S.kind[sIdx]) return;
    const int tid = threadIdx.x;
#pragma unroll
    for (int e = 0; e < R / 64; ++e) {
        const int q = e * 256 + tid;
        const int r = q >> 2;
        float* ff = regs + e * 16;
        if (S.scale) {
            const int kabs = k0 + ((q & 3) << 4);
#pragma unroll
            for (int j = 0; j < 16; ++j) ff[j] *= S.scale[kabs + j];
        }
        s16x8 v0, v1;
#pragma unroll
        for (int j = 0; j < 8; ++j) {
            v0[j] = (short)f2bf(ff[j]);
            v1[j] = (short)f2bf(ff[j + 8]);
        }
        const int swz = (r & 7) << 4;
        *(s16x8*)(tile + r * 128 + ((((q & 3) << 5) + 0)  ^ swz)) = v0;
        *(s16x8*)(tile + r * 128 + ((((q & 3) << 5) + 16) ^ swz)) = v1;
    }
}

__device__ __forceinline__ bf16x8 ldfrag(const char* lds, int r, int ks, int g) {
    const char* p = lds + r * 128 + ((((ks << 2) + g) << 4) ^ ((r & 7) << 4));
    return __builtin_bit_cast(bf16x8, *(const s16x8*)p);
}

// per-wave 32 rows x 64 cols ; acc[2][4]
__device__ __forceinline__ void compute_tile64(f32x4 (&acc)[2][4],
                                               const char* At, const char* Wt) {
    const int l   = threadIdx.x & 63;
    const int w   = threadIdx.x >> 6;
    const int wr  = (w >> 1) << 5;
    const int wc  = (w & 1) << 6;
    const int g   = l >> 4;
    const int r15 = l & 15;
#pragma unroll
    for (int ks = 0; ks < 2; ++ks) {
        bf16x8 a[2], b[4];
#pragma unroll
        for (int f = 0; f < 2; ++f) a[f] = ldfrag(At, wr + f * 16 + r15, ks, g);
#pragma unroll
        for (int f = 0; f < 4; ++f) b[f] = ldfrag(Wt, wc + f * 16 + r15, ks, g);
#pragma unroll
        for (int i = 0; i < 2; ++i)
#pragma unroll
            for (int j = 0; j < 4; ++j)
                acc[i][j] = __builtin_amdgcn_mfma_f32_16x16x32_bf16(a[i], b[j], acc[i][j], 0, 0, 0);
    }
}

// ---- counted-vmcnt double-buffered pipeline (all-bf16 sources) --------------
// Per tile each wave issues exactly 6 gll16 (A:2, W:4). After issuing tile
// t+1, vmcnt(6) => own tile-t loads landed; s_barrier => all waves' landed.
// Second barrier protects buffer reuse. Loads stay in flight across barriers.
template <int NT1, int NT2>
__device__ __forceinline__ void gemm_pipe(
        f32x4 (&acc1)[2][4], f32x4 (&acc2)[2][4],
        char* Ab0, char* Ab1, char* Wb0, char* Wb1,
        const KSrc& A1s, const KSrc& W1s, const KSrc& A2s, const KSrc& W2s,
        int row0, int col0) {
    constexpr int NT = NT1 + NT2;
    stage_b<64> (Ab0, A1s.p[0], A1s.ld[0], row0, 0);
    stage_b<128>(Wb0, W1s.p[0], W1s.ld[0], col0, 0);
#pragma unroll
    for (int kt = 0; kt < NT; ++kt) {
        char* Ac = (kt & 1) ? Ab1 : Ab0;
        char* Wc = (kt & 1) ? Wb1 : Wb0;
        if (kt + 1 < NT) {
            char* An = (kt & 1) ? Ab0 : Ab1;
            char* Wn = (kt & 1) ? Wb0 : Wb1;
            const int t = kt + 1;
            if (t < NT1) {
                stage_b<64> (An, A1s.p[t >> 1], A1s.ld[t >> 1], row0, t * 64);
                stage_b<128>(Wn, W1s.p[t >> 1], W1s.ld[t >> 1], col0, t * 64);
            } else {
                const int u = t - NT1;
                stage_b<64> (An, A2s.p[u >> 1], A2s.ld[u >> 1], row0, u * 64);
                stage_b<128>(Wn, W2s.p[u >> 1], W2s.ld[u >> 1], col0, u * 64);
            }
            asm volatile("s_waitcnt vmcnt(6)" ::: "memory");
        } else {
            asm volatile("s_waitcnt vmcnt(0)" ::: "memory");
        }
        __builtin_amdgcn_s_barrier();
        __builtin_amdgcn_sched_barrier(0);
        if (kt < NT1) compute_tile64(acc1, Ac, Wc);
        else          compute_tile64(acc2, Ac, Wc);
        __builtin_amdgcn_s_barrier();
    }
}

// ---- legacy single-buffer drain core (fallback + fac) -----------------------
template <int NT>
__device__ __forceinline__ void gemm1(f32x4 (&acc)[2][4], char* At, char* Wt,
                                      const KSrc& A, const KSrc& W,
                                      int row0, int col0) {
    float ra[16], rw[32];
#pragma unroll
    for (int kt = 0; kt < NT; ++kt) {
        const int s = kt >> 1;
        __syncthreads();
        stage_issue<64> (At, A, row0, kt * 64, s, ra);
        stage_issue<128>(Wt, W, col0, kt * 64, s, rw);
        stage_write<64> (At, A, row0, kt * 64, s, ra);
        stage_write<128>(Wt, W, col0, kt * 64, s, rw);
        __syncthreads();
        compute_tile64(acc, At, Wt);
    }
}

#define PIPE_SHARED  __shared__ alignas(16) char Ab0[8192], Ab1[8192], Wb0[16384], Wb1[16384];
#define GEMM_SHARED  __shared__ alignas(16) char At[8192], Wt[16384];
#define EPILOGUE_IDX                                                        \
    const int l  = threadIdx.x & 63;                                        \
    const int w  = threadIdx.x >> 6;                                        \
    const int wr = (w >> 1) << 5;                                           \
    const int wc = (w & 1) << 6;

// ---------------------------------------------------------- preconversion ---
__global__ __launch_bounds__(256) void k_pre_h(const float* __restrict__ x,
                                               const float* __restrict__ h0,
                                               unsigned short* __restrict__ wsh) {
#pragma unroll
    for (int e = 0; e < 4; ++e) {
        const int q   = blockIdx.x * 1024 + e * 256 + threadIdx.x;
        const int row = q >> 7;
        const int c8  = (q & 127) << 3;
        const float* src;
        if (c8 < 768)      src = h0 + (size_t)row * HD + c8;
        else if (c8 < 896) src = h0 + (size_t)row * HD + c8 + 384;  // factor
        else               src = x + (size_t)row * 128 + (c8 - 896);
        float4 f0 = *(const float4*)(src + 0);
        float4 f1 = *(const float4*)(src + 4);
        const float ff[8] = {f0.x, f0.y, f0.z, f0.w, f1.x, f1.y, f1.z, f1.w};
        s16x8 v;
#pragma unroll
        for (int j = 0; j < 8; ++j) v[j] = (short)f2bf(ff[j]);
        *(s16x8*)(wsh + (size_t)row * 1024 + c8) = v;
    }
}

__global__ __launch_bounds__(256) void k_pre_w(const float* __restrict__ cw,
                                               const float* __restrict__ cwh,
                                               const float* __restrict__ cow,
                                               const float* __restrict__ gwi,
                                               const float* __restrict__ gwh,
                                               unsigned short* __restrict__ dst) {
    const int q = blockIdx.x * 256 + threadIdx.x;
    const size_t eo = (size_t)q * 8;
    const float* src;
    if      (eo < 196608) src = cw  + eo;
    else if (eo < 393216) src = cwh + (eo - 196608);
    else if (eo < 458752) src = cow + (eo - 393216);
    else if (eo < 655360) src = gwi + (eo - 458752);
    else                  src = gwh + (eo - 655360);
    float4 f0 = *(const float4*)(src + 0);
    float4 f1 = *(const float4*)(src + 4);
    const float ff[8] = {f0.x, f0.y, f0.z, f0.w, f1.x, f1.y, f1.z, f1.w};
    s16x8 v;
#pragma unroll
    for (int j = 0; j < 8; ++j) v[j] = (short)f2bf(ff[j]);
    *(s16x8*)(dst + eo) = v;
}

__global__ __launch_bounds__(256) void k_pre_fw(const float* __restrict__ fw,
                                                unsigned short* __restrict__ dst) {
    const int col = blockIdx.x * 256 + threadIdx.x;
    float s = 0.f;
    for (int r = 0; r < 128; ++r) {
        float a = fw[r * 512 + col];
        s = fmaf(a, a, s);
    }
    const float inv = 1.0f / fmaxf(sqrtf(s), 1e-12f);
    for (int r = 0; r < 128; ++r)
        dst[r * 512 + col] = f2bf(fw[r * 512 + col] * inv);
}

// ------------------------------------------------------------------ con_r ---
template <bool PRE>
__global__ __launch_bounds__(256) void k_con_r(
    const float* __restrict__ x, const float* __restrict__ h0,
    const float* __restrict__ wih, const float* __restrict__ bih,
    const float* __restrict__ whh, const float* __restrict__ bhh,
    const unsigned short* __restrict__ ws, float* __restrict__ out) {
    const int lb   = xswz();
    const int col0 = (lb & 1) * 128;
    const int row0 = (lb >> 1) * 64;
    f32x4 acc[2][4] = {};
    if constexpr (PRE) {
        PIPE_SHARED
        KSrc A = {{ws + 896, ws + 640, ws + 256, ws + 256, nullptr},
                  {1024, 1024, 1024, 1024, 0}, {1, 1, 1, 1, 0}, nullptr};
        KSrc W = {{ws + OFF_CW + 65536, ws + OFF_CW + 65536,
                   ws + OFF_CWH + 65536 - 256, ws + OFF_CWH + 65536 - 256, nullptr},
                  {256, 256, 256, 256, 0}, {1, 1, 1, 1, 0}, nullptr};
        gemm_pipe<8, 0>(acc, acc, Ab0, Ab1, Wb0, Wb1, A, W, A, W, row0, col0);
    } else {
        GEMM_SHARED
        KSrc A = {{x, h0 + 1024, h0 + 256, h0 + 256, nullptr},
                  {128, HD, HD, HD, 0}, {0, 0, 0, 0, 0}, nullptr};
        KSrc W = {{wih + 65536, wih + 65536, whh + 65536 - 256, whh + 65536 - 256, nullptr},
                  {256, 256, 256, 256, 0}, {0, 0, 0, 0, 0}, nullptr};
        gemm1<8>(acc, At, Wt, A, W, row0, col0);
    }
    EPILOGUE_IDX
    unsigned short* outs = (unsigned short*)out;
#pragma unroll
    for (int i = 0; i < 2; ++i)
#pragma unroll
        for (int j = 0; j < 4; ++j)
#pragma unroll
            for (int t = 0; t < 4; ++t) {
                int row = row0 + wr + i * 16 + (l >> 4) * 4 + t;
                int c   = col0 + wc + j * 16 + (l & 15);
                float rv = sigm(acc[i][j][t] + bih[256 + c] + bhh[256 + c]);
                float hv = h0[(size_t)row * HD + 512 + c];
                outs[(size_t)row * 2560 + 512 + c] = f2bf(rv * hv);    // rh_C
            }
}

// ----------------------------------------------------------------- con_zn ---
template <bool PRE>
__global__ __launch_bounds__(256) void k_con_zn(
    const float* __restrict__ x, const float* __restrict__ h0,
    const float* __restrict__ wih, const float* __restrict__ bih,
    const float* __restrict__ whh, const float* __restrict__ bhh,
    const unsigned short* __restrict__ ws, float* __restrict__ out) {
    const int lb   = xswz();
    const int col0 = (lb & 1) * 128;
    const int row0 = (lb >> 1) * 64;
    const unsigned short* outs = (const unsigned short*)out;
    f32x4 aZ[2][4] = {}, aN[2][4] = {};
    if constexpr (PRE) {
        PIPE_SHARED
        KSrc Az = {{ws + 896, ws + 640, ws + 256, ws + 256, nullptr},
                   {1024, 1024, 1024, 1024, 0}, {1, 1, 1, 1, 0}, nullptr};
        KSrc Wz = {{ws + OFF_CW, ws + OFF_CW, ws + OFF_CWH - 256, ws + OFF_CWH - 256, nullptr},
                   {256, 256, 256, 256, 0}, {1, 1, 1, 1, 0}, nullptr};
        KSrc An = {{ws + 896, ws + 640, outs + 256, outs + 256, nullptr},
                   {1024, 1024, 2560, 2560, 0}, {1, 1, 1, 1, 0}, nullptr};
        KSrc Wn = {{ws + OFF_CW + 512 * 256, ws + OFF_CW + 512 * 256,
                    ws + OFF_CWH + 512 * 256 - 256, ws + OFF_CWH + 512 * 256 - 256, nullptr},
                   {256, 256, 256, 256, 0}, {1, 1, 1, 1, 0}, nullptr};
        gemm_pipe<8, 8>(aZ, aN, Ab0, Ab1, Wb0, Wb1, Az, Wz, An, Wn, row0, col0);
    } else {
        GEMM_SHARED
        KSrc Az = {{x, h0 + 1024, h0 + 256, h0 + 256, nullptr},
                   {128, HD, HD, HD, 0}, {0, 0, 0, 0, 0}, nullptr};
        KSrc Wz = {{wih, wih, whh - 256, whh - 256, nullptr},
                   {256, 256, 256, 256, 0}, {0, 0, 0, 0, 0}, nullptr};
        KSrc An = {{x, h0 + 1024, outs + 256, outs + 256, nullptr},
                   {128, HD, 2560, 2560, 0}, {0, 0, 1, 1, 0}, nullptr};
        KSrc Wn = {{wih + 512 * 256, wih + 512 * 256,
                    whh + 512 * 256 - 256, whh + 512 * 256 - 256, nullptr},
                   {256, 256, 256, 256, 0}, {0, 0, 0, 0, 0}, nullptr};
        gemm1<8>(aZ, At, Wt, Az, Wz, row0, col0);
        gemm1<8>(aN, At, Wt, An, Wn, row0, col0);
    }
    EPILOGUE_IDX
    unsigned short* outw = (unsigned short*)out;
#pragma unroll
    for (int i = 0; i < 2; ++i)
#pragma unroll
        for (int j = 0; j < 4; ++j)
#pragma unroll
            for (int t = 0; t < 4; ++t) {
                int row = row0 + wr + i * 16 + (l >> 4) * 4 + t;
                int c   = col0 + wc + j * 16 + (l & 15);
                float zv = sigm(aZ[i][j][t] + bih[c] + bhh[c]);
                float nv = tanhf(aN[i][j][t] + bih[512 + c] + bhh[512 + c]);
                float hv = h0[(size_t)row * HD + 512 + c];
                float hp = zv * hv + (1.0f - zv) * nv;
                hp = fminf(fmaxf(hp, -CLIPV), CLIPV);
                out[(size_t)row * HD + 512 + c] = hp;
                if (PRE) outw[(size_t)row * 2560 + 768 + c] = f2bf(hp); // cs_b
            }
}

// --------------------------------------------------------------------- co ---
template <bool PRE>
__global__ __launch_bounds__(256) void k_co(
    const float* __restrict__ cw, const float* __restrict__ cb,
    const unsigned short* __restrict__ ws, float* __restrict__ out) {
    const int lb   = xswz();
    const int col0 = (lb & 1) * 128;
    const int row0 = (lb >> 1) * 64;
    const unsigned short* outs = (const unsigned short*)out;
    f32x4 acc[2][4] = {};
    if constexpr (PRE) {
        PIPE_SHARED
        KSrc A = {{outs + 768, outs + 768, nullptr, nullptr, nullptr},
                  {2560, 2560, 0, 0, 0}, {1, 1, 0, 0, 0}, nullptr};   // cs_b
        KSrc W = {{ws + OFF_COW, ws + OFF_COW, nullptr, nullptr, nullptr},
                  {256, 256, 0, 0, 0}, {1, 1, 0, 0, 0}, nullptr};
        gemm_pipe<4, 0>(acc, acc, Ab0, Ab1, Wb0, Wb1, A, W, A, W, row0, col0);
    } else {
        GEMM_SHARED
        KSrc A = {{out + 512, out + 512, nullptr, nullptr, nullptr},
                  {HD, HD, 0, 0, 0}, {0, 0, 0, 0, 0}, nullptr};
        KSrc W = {{cw, cw, nullptr, nullptr, nullptr},
                  {256, 256, 0, 0, 0}, {0, 0, 0, 0, 0}, nullptr};
        gemm1<4>(acc, At, Wt, A, W, row0, col0);
    }
    EPILOGUE_IDX
    unsigned short* outw = (unsigned short*)out;
#pragma unroll
    for (int i = 0; i < 2; ++i)
#pragma unroll
        for (int j = 0; j < 4; ++j)
#pragma unroll
            for (int t = 0; t < 4; ++t) {
                int row = row0 + wr + i * 16 + (l >> 4) * 4 + t;
                int c   = col0 + wc + j * 16 + (l & 15);
                float v = acc[i][j][t] + cb[c];
                if (c < 128) {                         // co_mean
                    out[(size_t)row * HD + 1024 + c]    = v;           // gen_input
                    outw[(size_t)row * 2560 + 2304 + c] = f2bf(v);     // gi_b
                    if (PRE) out[(size_t)row * HD + 768 + c] = v;      // mean out
                } else if (PRE) {
                    out[(size_t)row * HD + 896 + (c - 128)] = v;       // logstd
                }
            }
}

// ------------------------------------------------------------------ gen_r ---
template <bool PRE>
__global__ __launch_bounds__(256) void k_gen_r(
    const float* __restrict__ h0,
    const float* __restrict__ wih, const float* __restrict__ bih,
    const float* __restrict__ whh, const float* __restrict__ bhh,
    unsigned short* __restrict__ ws, float* __restrict__ out) {
    const int lb   = xswz();
    const int col0 = (lb & 3) * 128;
    const int row0 = (lb >> 2) * 64;
    const unsigned short* outs = (const unsigned short*)out;
    f32x4 acc[2][4] = {};
    if constexpr (PRE) {
        PIPE_SHARED
        KSrc A = {{outs + 2304, ws - 128, ws - 128, ws - 128, ws - 128},
                  {2560, 1024, 1024, 1024, 1024}, {1, 1, 1, 1, 1}, nullptr};
        KSrc W = {{ws + OFF_GWI + 65536, ws + OFF_GWH + 512 * 512 - 128,
                   ws + OFF_GWH + 512 * 512 - 128, ws + OFF_GWH + 512 * 512 - 128,
                   ws + OFF_GWH + 512 * 512 - 128},
                  {128, 512, 512, 512, 512}, {1, 1, 1, 1, 1}, nullptr};
        gemm_pipe<10, 0>(acc, acc, Ab0, Ab1, Wb0, Wb1, A, W, A, W, row0, col0);
    } else {
        GEMM_SHARED
        KSrc A = {{outs + 2304, h0 - 128, h0 - 128, h0 - 128, h0 - 128},
                  {2560, HD, HD, HD, HD}, {1, 0, 0, 0, 0}, nullptr};
        KSrc W = {{wih + 65536, whh + 512 * 512 - 128, whh + 512 * 512 - 128,
                   whh + 512 * 512 - 128, whh + 512 * 512 - 128},
                  {128, 512, 512, 512, 512}, {0, 0, 0, 0, 0}, nullptr};
        gemm1<10>(acc, At, Wt, A, W, row0, col0);
    }
    EPILOGUE_IDX
    unsigned short* outw = (unsigned short*)out;
#pragma unroll
    for (int i = 0; i < 2; ++i)
#pragma unroll
        for (int j = 0; j < 4; ++j)
#pragma unroll
            for (int t = 0; t < 4; ++t) {
                int row = row0 + wr + i * 16 + (l >> 4) * 4 + t;
                int c   = col0 + wc + j * 16 + (l & 15);
                float rv = sigm(acc[i][j][t] + bih[512 + c] + bhh[512 + c]);
                float hv = h0[(size_t)row * HD + c];
                unsigned short rh = f2bf(rv * hv);
                if (PRE) ws  [(size_t)row * 1024 + 512 + c]  = rh;     // rh_G (panel)
                else     outw[(size_t)row * 2560 + 1536 + c] = rh;     // rh_G (out)
            }
}

// ----------------------------------------------------------------- gen_zn ---
template <bool PRE>
__global__ __launch_bounds__(256) void k_gen_zn(
    const float* __restrict__ h0,
    const float* __restrict__ wih, const float* __restrict__ bih,
    const float* __restrict__ whh, const float* __restrict__ bhh,
    const unsigned short* __restrict__ ws, float* __restrict__ out) {
    const int lb   = xswz();
    const int col0 = (lb & 3) * 128;
    const int row0 = (lb >> 2) * 64;
    const unsigned short* outs = (const unsigned short*)out;
    f32x4 aZ[2][4] = {}, aN[2][4] = {};
    if constexpr (PRE) {
        PIPE_SHARED
        KSrc Az = {{outs + 2304, ws - 128, ws - 128, ws - 128, ws - 128},
                   {2560, 1024, 1024, 1024, 1024}, {1, 1, 1, 1, 1}, nullptr};
        KSrc Wz = {{ws + OFF_GWI, ws + OFF_GWH - 128, ws + OFF_GWH - 128,
                    ws + OFF_GWH - 128, ws + OFF_GWH - 128},
                   {128, 512, 512, 512, 512}, {1, 1, 1, 1, 1}, nullptr};
        KSrc An = {{outs + 2304, ws + 384, ws + 384, ws + 384, ws + 384},
                   {2560, 1024, 1024, 1024, 1024}, {1, 1, 1, 1, 1}, nullptr};
        KSrc Wn = {{ws + OFF_GWI + 1024 * 128, ws + OFF_GWH + 1024 * 512 - 128,
                    ws + OFF_GWH + 1024 * 512 - 128, ws + OFF_GWH + 1024 * 512 - 128,
                    ws + OFF_GWH + 1024 * 512 - 128},
                   {128, 512, 512, 512, 512}, {1, 1, 1, 1, 1}, nullptr};
        gemm_pipe<10, 10>(aZ, aN, Ab0, Ab1, Wb0, Wb1, Az, Wz, An, Wn, row0, col0);
    } else {
        GEMM_SHARED
        KSrc Az = {{outs + 2304, h0 - 128, h0 - 128, h0 - 128, h0 - 128},
                   {2560, HD, HD, HD, HD}, {1, 0, 0, 0, 0}, nullptr};
        KSrc Wz = {{wih, whh - 128, whh - 128, whh - 128, whh - 128},
                   {128, 512, 512, 512, 512}, {0, 0, 0, 0, 0}, nullptr};
        KSrc An = {{outs + 2304, outs + 1408, outs + 1408, outs + 1408, outs + 1408},
                   {2560, 2560, 2560, 2560, 2560}, {1, 1, 1, 1, 1}, nullptr};
        KSrc Wn = {{wih + 1024 * 128, whh + 1024 * 512 - 128, whh + 1024 * 512 - 128,
                    whh + 1024 * 512 - 128, whh + 1024 * 512 - 128},
                   {128, 512, 512, 512, 512}, {0, 0, 0, 0, 0}, nullptr};
        gemm1<10>(aZ, At, Wt, Az, Wz, row0, col0);
        gemm1<10>(aN, At, Wt, An, Wn, row0, col0);
    }
    EPILOGUE_IDX
#pragma unroll
    for (int i = 0; i < 2; ++i)
#pragma unroll
        for (int j = 0; j < 4; ++j)
#pragma unroll
            for (int t = 0; t < 4; ++t) {
                int row = row0 + wr + i * 16 + (l >> 4) * 4 + t;
                int c   = col0 + wc + j * 16 + (l & 15);
                float zv = sigm(aZ[i][j][t] + bih[c] + bhh[c]);
                float nv = tanhf(aN[i][j][t] + bih[1024 + c] + bhh[1024 + c]);
                float hv = h0[(size_t)row * HD + c];
                float hp = zv * hv + (1.0f - zv) * nv;
                out[(size_t)row * HD + c] = fminf(fmaxf(hp, -CLIPV), CLIPV);
            }
}

// -------------------------------------------------------------------- fac ---
template <bool PRE>
__global__ __launch_bounds__(256) void k_fac(
    const float* __restrict__ fw,
    const unsigned short* __restrict__ ws, float* __restrict__ out) {
    GEMM_SHARED
    __shared__ float invn[512];
    const int row0 = xswz() * 64;
    if constexpr (!PRE) {
        const int t = threadIdx.x;
        float s0 = 0.f, s1 = 0.f;
        for (int r = 0; r < 128; ++r) {
            float a0 = fw[r * 512 + t];
            float a1 = fw[r * 512 + t + 256];
            s0 = fmaf(a0, a0, s0);
            s1 = fmaf(a1, a1, s1);
        }
        invn[t]       = 1.0f / fmaxf(sqrtf(s0), 1e-12f);
        invn[t + 256] = 1.0f / fmaxf(sqrtf(s1), 1e-12f);
        __syncthreads();
    }
    KSrc A = {{out, out, out, out, nullptr},
              {HD, HD, HD, HD, 0}, {0, 0, 0, 0, 0}, nullptr};
    KSrc W;
    if (PRE) {
        W = {{ws + OFF_FW, ws + OFF_FW, ws + OFF_FW, ws + OFF_FW, nullptr},
             {512, 512, 512, 512, 0}, {1, 1, 1, 1, 0}, nullptr};
    } else {
        W = {{fw, fw, fw, fw, nullptr},
             {512, 512, 512, 512, 0}, {0, 0, 0, 0, 0}, invn};
    }
    f32x4 acc[2][4] = {};
    gemm1<8>(acc, At, Wt, A, W, row0, 0);
    EPILOGUE_IDX
#pragma unroll
    for (int i = 0; i < 2; ++i)
#pragma unroll
        for (int j = 0; j < 4; ++j)
#pragma unroll
            for (int t = 0; t < 4; ++t) {
                int row = row0 + wr + i * 16 + (l >> 4) * 4 + t;
                int c   = wc + j * 16 + (l & 15);
                out[(size_t)row * HD + 1152 + c] = acc[i][j][t];
            }
}

// --------------------------------------------------- co_fin (fallback only) --
__global__ __launch_bounds__(256) void k_co_fin(
    const float* __restrict__ cw, const float* __restrict__ cb,
    float* __restrict__ out) {
    GEMM_SHARED
    const int row0 = xswz() * 64;
    KSrc A = {{out + 512, out + 512, nullptr, nullptr, nullptr},
              {HD, HD, 0, 0, 0}, {0, 0, 0, 0, 0}, nullptr};
    KSrc W = {{cw + 128 * 256, cw + 128 * 256, nullptr, nullptr, nullptr},
              {256, 256, 0, 0, 0}, {0, 0, 0, 0, 0}, nullptr};
    f32x4 acc[2][4] = {};
    gemm1<4>(acc, At, Wt, A, W, row0, 0);
    EPILOGUE_IDX
#pragma unroll
    for (int i = 0; i < 2; ++i)
#pragma unroll
        for (int j = 0; j < 4; ++j)
#pragma unroll
            for (int t = 0; t < 4; ++t) {
                int row = row0 + wr + i * 16 + (l >> 4) * 4 + t;
                int c   = wc + j * 16 + (l & 15);
                out[(size_t)row * HD + 896 + c] = acc[i][j][t] + cb[128 + c];
            }
#pragma unroll
    for (int e = 0; e < 8; ++e) {
        int idx = threadIdx.x + e * 256;
        int r   = idx >> 5;
        int cc  = (idx & 31) << 2;
        *(float4*)&out[(size_t)(row0 + r) * HD + 768 + cc] =
            *(const float4*)&out[(size_t)(row0 + r) * HD + 1024 + cc];
    }
}

// ----------------------------------------------------------------- launch ---
extern "C" void kernel_launch(void* const* d_in, const int* in_sizes, int n_in,
                              void* d_out, int out_size, void* d_ws, size_t ws_size,
                              hipStream_t stream) {
    const float* x    = (const float*)d_in[0];
    const float* h0   = (const float*)d_in[1];
    const float* cwih = (const float*)d_in[2];
    const float* cbih = (const float*)d_in[3];
    const float* cwhh = (const float*)d_in[4];
    const float* cbhh = (const float*)d_in[5];
    const float* cow  = (const float*)d_in[6];
    const float* cob  = (const float*)d_in[7];
    const float* gwih = (const float*)d_in[8];
    const float* gbih = (const float*)d_in[9];
    const float* gwhh = (const float*)d_in[10];
    const float* gbhh = (const float*)d_in[11];
    const float* fw   = (const float*)d_in[12];
    float* out = (float*)d_out;
    unsigned short* ws = (unsigned short*)d_ws;

    const bool pre = (ws_size >= (size_t)WS_ELEMS * 2);
    if (pre) {
        k_pre_h <<<2048, 256, 0, stream>>>(x, h0, ws);
        k_pre_w <<<704,  256, 0, stream>>>(cwih, cwhh, cow, gwih, gwhh, ws + OFF_CW);
        k_pre_fw<<<2,    256, 0, stream>>>(fw, ws + OFF_FW);
        k_con_r <true><<<512,  256, 0, stream>>>(x, h0, cwih, cbih, cwhh, cbhh, ws, out);
        k_con_zn<true><<<512,  256, 0, stream>>>(x, h0, cwih, cbih, cwhh, cbhh, ws, out);
        k_co    <true><<<512,  256, 0, stream>>>(cow, cob, ws, out);
        k_gen_r <true><<<1024, 256, 0, stream>>>(h0, gwih, gbih, gwhh, gbhh, ws, out);
        k_gen_zn<true><<<1024, 256, 0, stream>>>(h0, gwih, gbih, gwhh, gbhh, ws, out);
        k_fac   <true><<<256,  256, 0, stream>>>(fw, ws, out);
    } else {
        k_con_r <false><<<512,  256, 0, stream>>>(x, h0, cwih, cbih, cwhh, cbhh, nullptr, out);
        k_con_zn<false><<<512,  256, 0, stream>>>(x, h0, cwih, cbih, cwhh, cbhh, nullptr, out);
        k_co    <false><<<512,  256, 0, stream>>>(cow, cob, nullptr, out);
        k_gen_r <false><<<1024, 256, 0, stream>>>(h0, gwih, gbih, gwhh, gbhh, nullptr, out);
        k_gen_zn<false><<<1024, 256, 0, stream>>>(h0, gwih, gbih, gwhh, gbhh, nullptr, out);
        k_fac   <false><<<256,  256, 0, stream>>>(fw, nullptr, out);
        k_co_fin<<<256, 256, 0, stream>>>(cow, cob, out);
    }
}